// Round 5
// baseline (1063.222 us; speedup 1.0000x reference)
//
#include <hip/hip_runtime.h>

constexpr int NN = 100000;   // nodes
constexpr int NE = 3200000;  // edges
constexpr int NG = 256;      // graphs
constexpr int NB = NN / 32;  // 3125 buckets of 32 nodes (exact)

// ---------- zero helper ----------
__global__ void k_zero_i(int* __restrict__ p, int n) {
  int i = blockIdx.x * blockDim.x + threadIdx.x;
  if (i < n) p[i] = 0;
}
__global__ void k_zero_f(float* __restrict__ p, int n) {
  int i = blockIdx.x * blockDim.x + threadIdx.x;
  if (i < n) p[i] = 0.0f;
}

// ---------- degree histogram ----------
__global__ void k_degi(const int* __restrict__ dst, int* __restrict__ degi, int E) {
  int i = blockIdx.x * blockDim.x + threadIdx.x;
  int stride = gridDim.x * blockDim.x;
  for (; i < E; i += stride) atomicAdd(&degi[dst[i]], 1);
}

__global__ void k_dinv(const int* __restrict__ degi, float* __restrict__ dinv, int n) {
  int i = blockIdx.x * blockDim.x + threadIdx.x;
  if (i < n) dinv[i] = rsqrtf((float)(degi[i] + 1));  // +1 self-loop
}

// ---------- single-block exclusive scan of degi -> rowstart[NN+1] ----------
__global__ void k_scan(const int* __restrict__ degi, int* __restrict__ rowstart) {
  constexpr int T = 1024;
  __shared__ int part[T];
  const int tid = threadIdx.x;
  const int chunk = (NN + T - 1) / T;
  const int lo = tid * chunk, hi = min(lo + chunk, NN);
  int s = 0;
  for (int i = lo; i < hi; ++i) s += degi[i];
  part[tid] = s;
  __syncthreads();
  for (int off = 1; off < T; off <<= 1) {
    int v = part[tid];
    int u = (tid >= off) ? part[tid - off] : 0;
    __syncthreads();
    part[tid] = v + u;
    __syncthreads();
  }
  int base = (tid > 0) ? part[tid - 1] : 0;
  for (int i = lo; i < hi; ++i) {
    rowstart[i] = base;
    base += degi[i];
  }
  if (tid == T - 1) rowstart[NN] = base;
}

// ---------- CSR pass 1: scatter packed (src, dst&31) into per-bucket regions ----------
// bucket b = dst>>5 covers nodes [32b,32b+32); its slot region is
// [rowstart[32b], rowstart[32b+32]) -- bucket bases come free from rowstart.
// Packed word: src | (dst&31)<<20   (src < 2^17 < 2^20).
__global__ void k_scatter_pairs(const int* __restrict__ src, const int* __restrict__ dst,
                                const int* __restrict__ rowstart, int* __restrict__ bcursor,
                                int* __restrict__ pairs, int E) {
  int i = blockIdx.x * blockDim.x + threadIdx.x;
  int stride = gridDim.x * blockDim.x;
  for (; i < E; i += stride) {
    int s = src[i], d = dst[i];
    int b = d >> 5;
    int base = rowstart[b << 5];  // 3125 distinct entries, L2-hot
    int p = base + atomicAdd(&bcursor[b], 1);
    pairs[p] = s | ((d & 31) << 20);
  }
}

// ---------- CSR pass 2: per-bucket local fill (LDS cursors, contiguous writes) ----------
__global__ void k_bucket_fill(const int* __restrict__ pairs, const int* __restrict__ rowstart,
                              int* __restrict__ csr_src) {
  __shared__ int cur[32];
  const int b = blockIdx.x;
  const int n0 = b << 5;
  if (threadIdx.x < 32) cur[threadIdx.x] = 0;
  __syncthreads();
  const int e0 = rowstart[n0], e1 = rowstart[n0 + 32];
  for (int e = e0 + threadIdx.x; e < e1; e += blockDim.x) {
    int v = pairs[e];
    int dl = v >> 20;
    int p = rowstart[n0 + dl] + atomicAdd(&cur[dl], 1);
    csr_src[p] = v & ((1 << 20) - 1);
  }
}

// ---------- dense transform t = h @ W ----------
template <int IN, int OUT, int ROWS>
__global__ void k_mm(const float* __restrict__ h, const float* __restrict__ W,
                     float* __restrict__ t, int n) {
  __shared__ float Ws[IN * OUT];
  __shared__ float Hs[ROWS][IN];
  const int tid = threadIdx.x;
  const int NT = ROWS * OUT;
  for (int i = tid; i < IN * OUT; i += NT) Ws[i] = W[i];
  const int row0 = blockIdx.x * ROWS;
  for (int i = tid; i < ROWS * IN; i += NT) {
    int rr = i / IN, kk = i - rr * IN;
    int gr = row0 + rr;
    Hs[rr][kk] = (gr < n) ? h[gr * IN + kk] : 0.0f;
  }
  __syncthreads();
  const int r = tid / OUT, c = tid - r * OUT;
  const int row = row0 + r;
  if (row < n) {
    float acc = 0.0f;
#pragma unroll
    for (int k = 0; k < IN; ++k) acc += Hs[r][k] * Ws[k * OUT + c];
    t[row * OUT + c] = acc;
  }
}

// ---------- gather aggregation, 64 feats: one wave per node ----------
template <bool RELU>
__global__ void k_gather64b(const float* __restrict__ t, const int* __restrict__ rowstart,
                            const int* __restrict__ csr_src,
                            const float* __restrict__ dinv, const float* __restrict__ b,
                            float* __restrict__ out) {
  const int wave = (blockIdx.x * blockDim.x + threadIdx.x) >> 6;
  const int lane = threadIdx.x & 63;
  if (wave >= NN) return;
  const int r0 = rowstart[wave], r1 = rowstart[wave + 1];
  const float di = dinv[wave];
  float acc = 0.0f;
  int e = r0;
  for (; e + 3 < r1; e += 4) {
    int s0 = csr_src[e], s1 = csr_src[e + 1], s2 = csr_src[e + 2], s3 = csr_src[e + 3];
    float w0 = dinv[s0], w1 = dinv[s1], w2 = dinv[s2], w3 = dinv[s3];
    float v0 = t[s0 * 64 + lane], v1 = t[s1 * 64 + lane];
    float v2 = t[s2 * 64 + lane], v3 = t[s3 * 64 + lane];
    acc += v0 * w0 + v1 * w1 + v2 * w2 + v3 * w3;
  }
  for (; e < r1; ++e) {
    int s = csr_src[e];
    acc += t[s * 64 + lane] * dinv[s];
  }
  float v = (acc + t[wave * 64 + lane] * di) * di + b[lane];
  out[wave * 64 + lane] = RELU ? fmaxf(v, 0.0f) : v;
}

// ---------- layer-3 gather (32 feats) fused with mean-pool partial sums ----------
__global__ void k_gather32_pool(const float* __restrict__ t, const int* __restrict__ rowstart,
                                const int* __restrict__ csr_src,
                                const float* __restrict__ dinv, const float* __restrict__ b,
                                const int* __restrict__ batch, float* __restrict__ psum) {
  const int wave = (blockIdx.x * blockDim.x + threadIdx.x) >> 6;
  const int lane = threadIdx.x & 63;
  if (wave >= NN) return;
  const int f = lane & 31, j = lane >> 5;  // two half-waves split edges
  const int r0 = rowstart[wave], r1 = rowstart[wave + 1];
  const float di = dinv[wave];
  float acc = 0.0f;
  int e = r0 + j;
  for (; e + 3 < r1; e += 4) {
    int s0 = csr_src[e], s1 = csr_src[e + 2];
    acc += t[s0 * 32 + f] * dinv[s0] + t[s1 * 32 + f] * dinv[s1];
  }
  for (; e < r1; e += 2) {
    int s = csr_src[e];
    acc += t[s * 32 + f] * dinv[s];
  }
  acc += __shfl_xor(acc, 32, 64);
  if (j == 0) {
    float v = (acc + t[wave * 32 + f] * di) * di + b[f];
    atomicAdd(&psum[batch[wave] * 32 + f], v);
  }
}

// ---------- counts from sorted batch + final divide ----------
__global__ void k_finalize(const float* __restrict__ psum, const int* __restrict__ batch,
                           float* __restrict__ out) {
  int i = blockIdx.x * blockDim.x + threadIdx.x;
  if (i >= NG * 32) return;
  int g = i >> 5;
  int lo = 0, hi = NN;
  while (lo < hi) { int m = (lo + hi) >> 1; if (batch[m] < g) lo = m + 1; else hi = m; }
  int a = lo;
  lo = 0; hi = NN;
  while (lo < hi) { int m = (lo + hi) >> 1; if (batch[m] < g + 1) lo = m + 1; else hi = m; }
  int cnt = lo - a;
  out[i] = psum[i] / fmaxf((float)cnt, 1.0f);
}

extern "C" void kernel_launch(void* const* d_in, const int* in_sizes, int n_in,
                              void* d_out, int out_size, void* d_ws, size_t ws_size,
                              hipStream_t stream) {
  const float* x  = (const float*)d_in[0];
  const int*   ei = (const int*)d_in[1];
  const int* batch = (const int*)d_in[2];
  const float* W1 = (const float*)d_in[3];
  const float* b1 = (const float*)d_in[4];
  const float* W2 = (const float*)d_in[5];
  const float* b2 = (const float*)d_in[6];
  const float* W3 = (const float*)d_in[7];
  const float* b3 = (const float*)d_in[8];
  float* out = (float*)d_out;

  const int* src = ei;        // edge_index[0]
  const int* dst = ei + NE;   // edge_index[1]

  // workspace layout (element offsets, 4B each)
  float* ws = (float*)d_ws;
  float* dinv     = ws;                          // NN               [0, 100000)
  int*   degi     = (int*)(ws + 100352);         // NN
  int*   bcursor  = (int*)(ws + 200704);         // NB (3125)
  int*   rowstart = (int*)(ws + 204160);         // NN+1
  int*   csr_src  = (int*)(ws + 304512);         // NE
  float* bufT     = ws + 3504512;                // NN*64  (pairs aliased here pre-layer1)
  float* bufH     = ws + 9904512;                // NN*64
  float* psum     = ws + 16304512;               // NG*32
  int*   pairs    = (int*)bufT;                  // NE ints, dead after k_bucket_fill

  const int B = 256;
  auto cdiv = [](int a, int b) { return (a + b - 1) / b; };

  // ---- build norm + CSR (shared across all 3 layers) ----
  // zero degi .. bcursor inclusive (one range, incl. 352-elem pad): 204160-100352 = 103808
  k_zero_i<<<cdiv(103808, B), B, 0, stream>>>(degi, 103808);
  k_degi<<<2048, B, 0, stream>>>(dst, degi, NE);
  k_dinv<<<cdiv(NN, B), B, 0, stream>>>(degi, dinv, NN);
  k_scan<<<1, 1024, 0, stream>>>(degi, rowstart);
  k_scatter_pairs<<<4096, B, 0, stream>>>(src, dst, rowstart, bcursor, pairs, NE);
  k_bucket_fill<<<NB, B, 0, stream>>>(pairs, rowstart, csr_src);

  // ---- layer 1: x(13) -> 64, relu ----
  k_mm<13, 64, 4><<<cdiv(NN, 4), B, 0, stream>>>(x, W1, bufT, NN);
  k_gather64b<true><<<cdiv(NN * 64, B), B, 0, stream>>>(bufT, rowstart, csr_src, dinv, b1, bufH);

  // ---- layer 2: 64 -> 64, relu ----
  k_mm<64, 64, 4><<<cdiv(NN, 4), B, 0, stream>>>(bufH, W2, bufT, NN);
  k_gather64b<true><<<cdiv(NN * 64, B), B, 0, stream>>>(bufT, rowstart, csr_src, dinv, b2, bufH);

  // ---- layer 3: 64 -> 32, fused with pool partial sums ----
  k_mm<64, 32, 8><<<cdiv(NN, 8), B, 0, stream>>>(bufH, W3, bufT, NN);
  k_zero_f<<<cdiv(NG * 32, B), B, 0, stream>>>(psum, NG * 32);
  k_gather32_pool<<<cdiv(NN * 64, B), B, 0, stream>>>(bufT, rowstart, csr_src, dinv, b3, batch, psum);

  // ---- finalize mean ----
  k_finalize<<<cdiv(NG * 32, B), B, 0, stream>>>(psum, batch, out);
}

// Round 6
// 839.562 us; speedup vs baseline: 1.2664x; 1.2664x over previous
//
#include <hip/hip_runtime.h>

constexpr int NN = 100000;   // nodes
constexpr int NE = 3200000;  // edges
constexpr int NG = 256;      // graphs
constexpr int NCB = 196;     // coarse buckets: dst>>9 (512 nodes each; 99999>>9 = 195)
constexpr int TILE = 4096;   // edges per msplit block
constexpr int EPT = TILE / 256;  // 16 edges per thread

// ---------- zero helpers ----------
__global__ void k_zero_i(int* __restrict__ p, int n) {
  int i = blockIdx.x * blockDim.x + threadIdx.x;
  if (i < n) p[i] = 0;
}
__global__ void k_zero_f(float* __restrict__ p, int n) {
  int i = blockIdx.x * blockDim.x + threadIdx.x;
  if (i < n) p[i] = 0.0f;
}

// ---------- degree histogram ----------
__global__ void k_degi(const int* __restrict__ dst, int* __restrict__ degi, int E) {
  int i = blockIdx.x * blockDim.x + threadIdx.x;
  int stride = gridDim.x * blockDim.x;
  for (; i < E; i += stride) atomicAdd(&degi[dst[i]], 1);
}

__global__ void k_dinv(const int* __restrict__ degi, float* __restrict__ dinv, int n) {
  int i = blockIdx.x * blockDim.x + threadIdx.x;
  if (i < n) dinv[i] = rsqrtf((float)(degi[i] + 1));  // +1 self-loop
}

// ---------- single-block exclusive scan of degi -> rowstart[NN+1] ----------
__global__ void k_scan(const int* __restrict__ degi, int* __restrict__ rowstart) {
  constexpr int T = 1024;
  __shared__ int part[T];
  const int tid = threadIdx.x;
  const int chunk = (NN + T - 1) / T;
  const int lo = tid * chunk, hi = min(lo + chunk, NN);
  int s = 0;
  for (int i = lo; i < hi; ++i) s += degi[i];
  part[tid] = s;
  __syncthreads();
  for (int off = 1; off < T; off <<= 1) {
    int v = part[tid];
    int u = (tid >= off) ? part[tid - off] : 0;
    __syncthreads();
    part[tid] = v + u;
    __syncthreads();
  }
  int base = (tid > 0) ? part[tid - 1] : 0;
  for (int i = lo; i < hi; ++i) {
    rowstart[i] = base;
    base += degi[i];
  }
  if (tid == T - 1) rowstart[NN] = base;
}

// ---------- CSR pass 1: tile-chunked multisplit into coarse-bucket regions ----------
// Each block owns one TILE of edges. It histograms them over NCB coarse buckets,
// grabs ONE contiguous chunk per bucket via a single global atomicAdd, then writes
// its edges into its own chunks -> every cache line is written by one CU in one
// burst (kills the cross-XCD partial-line write amplification seen in R4/R5).
// Packed word: src(17b) | (dst&511)<<17   (26 bits total).
__global__ void k_msplit(const int* __restrict__ src, const int* __restrict__ dst,
                         const int* __restrict__ rowstart, int* __restrict__ gcursor,
                         int* __restrict__ pairs, int E) {
  constexpr int NT = 256;
  __shared__ int hist[NCB], lbase[NCB], lcur[NCB], gwrite[NCB];
  const int tid = threadIdx.x;
  const int e0 = blockIdx.x * TILE;
  for (int i = tid; i < NCB; i += NT) { hist[i] = 0; lcur[i] = 0; }
  __syncthreads();
  int ls[EPT], ld[EPT];
#pragma unroll
  for (int i = 0; i < EPT; ++i) {
    int e = e0 + i * NT + tid;
    if (e < E) {
      ls[i] = src[e];
      ld[i] = dst[e];
      atomicAdd(&hist[ld[i] >> 9], 1);
    } else {
      ld[i] = -1;
    }
  }
  __syncthreads();
  if (tid == 0) {  // serial exclusive scan over 196 entries (once per block)
    int run = 0;
    for (int c = 0; c < NCB; ++c) { lbase[c] = run; run += hist[c]; }
  }
  __syncthreads();
  for (int c = tid; c < NCB; c += NT) {
    int cnt = hist[c];
    if (cnt > 0) {
      int g = atomicAdd(&gcursor[c], cnt);
      gwrite[c] = rowstart[c << 9] + g - lbase[c];  // bucket base comes free from rowstart
    }
  }
  __syncthreads();
#pragma unroll
  for (int i = 0; i < EPT; ++i) {
    if (ld[i] >= 0) {
      int c = ld[i] >> 9;
      int pos = lbase[c] + atomicAdd(&lcur[c], 1);
      pairs[gwrite[c] + pos] = ls[i] | ((ld[i] & 511) << 17);
    }
  }
}

// ---------- CSR pass 2: per-coarse-bucket fill (single-writer regions) ----------
__global__ void k_bfill(const int* __restrict__ pairs, const int* __restrict__ rowstart,
                        int* __restrict__ csr_src) {
  __shared__ int cur[512];
  const int cb = blockIdx.x;
  const int n0 = cb << 9;
  const int nEnd = min(NN, n0 + 512);
  for (int i = threadIdx.x; i < 512; i += blockDim.x) cur[i] = 0;
  __syncthreads();
  const int e0 = rowstart[n0], e1 = rowstart[nEnd];
  for (int e = e0 + (int)threadIdx.x; e < e1; e += blockDim.x) {
    int w = pairs[e];
    int dl = w >> 17;          // 0..511 (bit 31 clear)
    int s = w & 0x1FFFF;
    int p = rowstart[n0 + dl] + atomicAdd(&cur[dl], 1);
    csr_src[p] = s;
  }
}

// ---------- dense transform t' = (h @ W) * dinv[row] ----------
template <int IN, int OUT, int ROWS>
__global__ void k_mm(const float* __restrict__ h, const float* __restrict__ W,
                     const float* __restrict__ dinv, float* __restrict__ t, int n) {
  __shared__ float Ws[IN * OUT];
  __shared__ float Hs[ROWS][IN];
  const int tid = threadIdx.x;
  const int NT = ROWS * OUT;
  for (int i = tid; i < IN * OUT; i += NT) Ws[i] = W[i];
  const int row0 = blockIdx.x * ROWS;
  for (int i = tid; i < ROWS * IN; i += NT) {
    int rr = i / IN, kk = i - rr * IN;
    int gr = row0 + rr;
    Hs[rr][kk] = (gr < n) ? h[gr * IN + kk] : 0.0f;
  }
  __syncthreads();
  const int r = tid / OUT, c = tid - r * OUT;
  const int row = row0 + r;
  if (row < n) {
    float acc = 0.0f;
#pragma unroll
    for (int k = 0; k < IN; ++k) acc += Hs[r][k] * Ws[k * OUT + c];
    t[row * OUT + c] = acc * dinv[row];
  }
}

// ---------- gather aggregation, 64 feats: one wave per node ----------
// t' already carries dinv[src]; out = (self + sum t'[s]) * dinv[v] + b
template <bool RELU>
__global__ void k_gather64c(const float* __restrict__ t, const int* __restrict__ rowstart,
                            const int* __restrict__ csr_src,
                            const float* __restrict__ dinv, const float* __restrict__ b,
                            float* __restrict__ out) {
  const int wave = (blockIdx.x * blockDim.x + threadIdx.x) >> 6;
  const int lane = threadIdx.x & 63;
  if (wave >= NN) return;
  const int r0 = rowstart[wave], r1 = rowstart[wave + 1];
  float acc = t[wave * 64 + lane];  // self term (t' = t*dinv already)
  int e = r0;
  for (; e + 3 < r1; e += 4) {
    int s0 = csr_src[e], s1 = csr_src[e + 1], s2 = csr_src[e + 2], s3 = csr_src[e + 3];
    acc += t[s0 * 64 + lane] + t[s1 * 64 + lane] + t[s2 * 64 + lane] + t[s3 * 64 + lane];
  }
  for (; e < r1; ++e) acc += t[csr_src[e] * 64 + lane];
  float v = acc * dinv[wave] + b[lane];
  out[wave * 64 + lane] = RELU ? fmaxf(v, 0.0f) : v;
}

// ---------- layer-3 gather (32 feats) fused with mean-pool partial sums ----------
__global__ void k_gather32_pool(const float* __restrict__ t, const int* __restrict__ rowstart,
                                const int* __restrict__ csr_src,
                                const float* __restrict__ dinv, const float* __restrict__ b,
                                const int* __restrict__ batch, float* __restrict__ psum) {
  const int wave = (blockIdx.x * blockDim.x + threadIdx.x) >> 6;
  const int lane = threadIdx.x & 63;
  if (wave >= NN) return;
  const int f = lane & 31, j = lane >> 5;  // two half-waves split edges
  const int r0 = rowstart[wave], r1 = rowstart[wave + 1];
  float acc = (j == 0) ? t[wave * 32 + f] : 0.0f;  // self term
  int e = r0 + j;
  for (; e + 3 < r1; e += 4) {
    int s0 = csr_src[e], s1 = csr_src[e + 2];
    acc += t[s0 * 32 + f] + t[s1 * 32 + f];
  }
  for (; e < r1; e += 2) acc += t[csr_src[e] * 32 + f];
  acc += __shfl_xor(acc, 32, 64);
  if (j == 0) {
    float v = acc * dinv[wave] + b[f];
    atomicAdd(&psum[batch[wave] * 32 + f], v);
  }
}

// ---------- counts from sorted batch + final divide ----------
__global__ void k_finalize(const float* __restrict__ psum, const int* __restrict__ batch,
                           float* __restrict__ out) {
  int i = blockIdx.x * blockDim.x + threadIdx.x;
  if (i >= NG * 32) return;
  int g = i >> 5;
  int lo = 0, hi = NN;
  while (lo < hi) { int m = (lo + hi) >> 1; if (batch[m] < g) lo = m + 1; else hi = m; }
  int a = lo;
  lo = 0; hi = NN;
  while (lo < hi) { int m = (lo + hi) >> 1; if (batch[m] < g + 1) lo = m + 1; else hi = m; }
  int cnt = lo - a;
  out[i] = psum[i] / fmaxf((float)cnt, 1.0f);
}

extern "C" void kernel_launch(void* const* d_in, const int* in_sizes, int n_in,
                              void* d_out, int out_size, void* d_ws, size_t ws_size,
                              hipStream_t stream) {
  const float* x  = (const float*)d_in[0];
  const int*   ei = (const int*)d_in[1];
  const int* batch = (const int*)d_in[2];
  const float* W1 = (const float*)d_in[3];
  const float* b1 = (const float*)d_in[4];
  const float* W2 = (const float*)d_in[5];
  const float* b2 = (const float*)d_in[6];
  const float* W3 = (const float*)d_in[7];
  const float* b3 = (const float*)d_in[8];
  float* out = (float*)d_out;

  const int* src = ei;        // edge_index[0]
  const int* dst = ei + NE;   // edge_index[1]

  // workspace layout (element offsets, 4B each)
  float* ws = (float*)d_ws;
  float* dinv     = ws;                          // NN
  int*   degi     = (int*)(ws + 100352);         // NN   (zeroed jointly with gcursor)
  int*   gcursor  = (int*)(ws + 200704);         // NCB
  int*   rowstart = (int*)(ws + 204160);         // NN+1
  int*   csr_src  = (int*)(ws + 304512);         // NE
  float* bufT     = ws + 3504512;                // NN*64  (pairs aliased here pre-layer1)
  float* bufH     = ws + 9904512;                // NN*64
  float* psum     = ws + 16304512;               // NG*32
  int*   pairs    = (int*)bufT;                  // NE ints, dead after k_bfill

  const int B = 256;
  auto cdiv = [](int a, int b) { return (a + b - 1) / b; };

  // ---- build norm + CSR (shared across all 3 layers) ----
  // zero degi .. gcursor inclusive (one range incl. pads): 204160-100352 = 103808
  k_zero_i<<<cdiv(103808, B), B, 0, stream>>>(degi, 103808);
  k_degi<<<2048, B, 0, stream>>>(dst, degi, NE);
  k_dinv<<<cdiv(NN, B), B, 0, stream>>>(degi, dinv, NN);
  k_scan<<<1, 1024, 0, stream>>>(degi, rowstart);
  k_msplit<<<cdiv(NE, TILE), B, 0, stream>>>(src, dst, rowstart, gcursor, pairs, NE);
  k_bfill<<<NCB, B, 0, stream>>>(pairs, rowstart, csr_src);

  // ---- layer 1: x(13) -> 64, relu ----
  k_mm<13, 64, 4><<<cdiv(NN, 4), B, 0, stream>>>(x, W1, dinv, bufT, NN);
  k_gather64c<true><<<cdiv(NN * 64, B), B, 0, stream>>>(bufT, rowstart, csr_src, dinv, b1, bufH);

  // ---- layer 2: 64 -> 64, relu ----
  k_mm<64, 64, 4><<<cdiv(NN, 4), B, 0, stream>>>(bufH, W2, dinv, bufT, NN);
  k_gather64c<true><<<cdiv(NN * 64, B), B, 0, stream>>>(bufT, rowstart, csr_src, dinv, b2, bufH);

  // ---- layer 3: 64 -> 32, fused with pool partial sums ----
  k_mm<64, 32, 8><<<cdiv(NN, 8), B, 0, stream>>>(bufH, W3, dinv, bufT, NN);
  k_zero_f<<<cdiv(NG * 32, B), B, 0, stream>>>(psum, NG * 32);
  k_gather32_pool<<<cdiv(NN * 64, B), B, 0, stream>>>(bufT, rowstart, csr_src, dinv, b3, batch, psum);

  // ---- finalize mean ----
  k_finalize<<<cdiv(NG * 32, B), B, 0, stream>>>(psum, batch, out);
}

// Round 7
// 679.760 us; speedup vs baseline: 1.5641x; 1.2351x over previous
//
#include <hip/hip_runtime.h>

constexpr int NN = 100000;   // nodes
constexpr int NE = 3200000;  // edges
constexpr int NG = 256;      // graphs
constexpr int NCB = 196;     // coarse buckets: dst>>9 (512 nodes each)
constexpr int TILE = 4096;   // edges per msplit block
constexpr int EPT = TILE / 256;
constexpr int NQ = NN / 4;       // 25000 int4 quads
constexpr int NSB = (NQ + 255) / 256;  // 98 scan blocks

// ---------- zero helpers ----------
__global__ void k_zero_i(int* __restrict__ p, int n) {
  int i = blockIdx.x * blockDim.x + threadIdx.x;
  if (i < n) p[i] = 0;
}
__global__ void k_zero_f(float* __restrict__ p, int n) {
  int i = blockIdx.x * blockDim.x + threadIdx.x;
  if (i < n) p[i] = 0.0f;
}

// ---------- degree histogram ----------
__global__ void k_degi(const int* __restrict__ dst, int* __restrict__ degi, int E) {
  int i = blockIdx.x * blockDim.x + threadIdx.x;
  int stride = gridDim.x * blockDim.x;
  for (; i < E; i += stride) atomicAdd(&degi[dst[i]], 1);
}

// ---------- scan phase 1: per-block (1024 elems) + fused dinv ----------
__global__ void k_scan1(const int* __restrict__ degi, int* __restrict__ rowstart,
                        int* __restrict__ bsum, float* __restrict__ dinv) {
  __shared__ int ts[256];
  const int t = threadIdx.x;
  const int i4 = blockIdx.x * 256 + t;
  int4 v = make_int4(0, 0, 0, 0);
  if (i4 < NQ) v = ((const int4*)degi)[i4];
  const int lsum = v.x + v.y + v.z + v.w;
  ts[t] = lsum;
  __syncthreads();
  for (int o = 1; o < 256; o <<= 1) {
    int a = ts[t];
    int u = (t >= o) ? ts[t - o] : 0;
    __syncthreads();
    ts[t] = a + u;
    __syncthreads();
  }
  if (i4 < NQ) {
    int pre = (t == 0) ? 0 : ts[t - 1];
    int4 r;
    r.x = pre;
    r.y = pre + v.x;
    r.z = pre + v.x + v.y;
    r.w = pre + v.x + v.y + v.z;
    ((int4*)rowstart)[i4] = r;
    float4 dv;
    dv.x = rsqrtf((float)(v.x + 1));
    dv.y = rsqrtf((float)(v.y + 1));
    dv.z = rsqrtf((float)(v.z + 1));
    dv.w = rsqrtf((float)(v.w + 1));
    ((float4*)dinv)[i4] = dv;
  }
  if (t == 255) bsum[blockIdx.x] = ts[255];
}

// ---------- scan phase 2: exclusive scan of 98 block sums ----------
__global__ void k_scan2(int* __restrict__ bsum) {
  __shared__ int s[128];
  const int t = threadIdx.x;
  s[t] = (t < NSB) ? bsum[t] : 0;
  __syncthreads();
  for (int o = 1; o < 128; o <<= 1) {
    int v = s[t];
    int u = (t >= o) ? s[t - o] : 0;
    __syncthreads();
    s[t] = v + u;
    __syncthreads();
  }
  if (t < NSB) bsum[t] = (t == 0) ? 0 : s[t - 1];
}

// ---------- scan phase 3: add block offsets; rowstart[NN] = NE ----------
__global__ void k_scan3(int* __restrict__ rowstart, const int* __restrict__ bsum) {
  const int i4 = blockIdx.x * 256 + threadIdx.x;
  if (i4 < NQ) {
    const int off = bsum[blockIdx.x];
    int4 r = ((int4*)rowstart)[i4];
    r.x += off; r.y += off; r.z += off; r.w += off;
    ((int4*)rowstart)[i4] = r;
  }
  if (blockIdx.x == 0 && threadIdx.x == 0) rowstart[NN] = NE;  // sum(deg) == E
}

// ---------- CSR pass 1: tile-chunked multisplit ----------
__global__ void k_msplit(const int* __restrict__ src, const int* __restrict__ dst,
                         const int* __restrict__ rowstart, int* __restrict__ gcursor,
                         int* __restrict__ pairs, int E) {
  constexpr int NT = 256;
  __shared__ int hist[NCB], lbase[NCB], lcur[NCB], gwrite[NCB];
  const int tid = threadIdx.x;
  const int e0 = blockIdx.x * TILE;
  for (int i = tid; i < NCB; i += NT) { hist[i] = 0; lcur[i] = 0; }
  __syncthreads();
  int ls[EPT], ld[EPT];
#pragma unroll
  for (int i = 0; i < EPT; ++i) {
    int e = e0 + i * NT + tid;
    if (e < E) {
      ls[i] = src[e];
      ld[i] = dst[e];
      atomicAdd(&hist[ld[i] >> 9], 1);
    } else {
      ld[i] = -1;
    }
  }
  __syncthreads();
  if (tid == 0) {
    int run = 0;
    for (int c = 0; c < NCB; ++c) { lbase[c] = run; run += hist[c]; }
  }
  __syncthreads();
  for (int c = tid; c < NCB; c += NT) {
    int cnt = hist[c];
    if (cnt > 0) {
      int g = atomicAdd(&gcursor[c], cnt);
      gwrite[c] = rowstart[c << 9] + g - lbase[c];
    }
  }
  __syncthreads();
#pragma unroll
  for (int i = 0; i < EPT; ++i) {
    if (ld[i] >= 0) {
      int c = ld[i] >> 9;
      int pos = lbase[c] + atomicAdd(&lcur[c], 1);
      pairs[gwrite[c] + pos] = ls[i] | ((ld[i] & 511) << 17);
    }
  }
}

// ---------- CSR pass 2: per-coarse-bucket fill ----------
__global__ void k_bfill(const int* __restrict__ pairs, const int* __restrict__ rowstart,
                        int* __restrict__ csr_src) {
  __shared__ int cur[512];
  const int cb = blockIdx.x;
  const int n0 = cb << 9;
  const int nEnd = min(NN, n0 + 512);
  for (int i = threadIdx.x; i < 512; i += blockDim.x) cur[i] = 0;
  __syncthreads();
  const int e0 = rowstart[n0], e1 = rowstart[nEnd];
  for (int e = e0 + (int)threadIdx.x; e < e1; e += blockDim.x) {
    int w = pairs[e];
    int dl = w >> 17;
    int s = w & 0x1FFFF;
    int p = rowstart[n0 + dl] + atomicAdd(&cur[dl], 1);
    csr_src[p] = s;
  }
}

// ---------- dense transform t' = (h @ W) * dinv[row] ----------
template <int IN, int OUT, int ROWS>
__global__ void k_mm(const float* __restrict__ h, const float* __restrict__ W,
                     const float* __restrict__ dinv, float* __restrict__ t, int n) {
  __shared__ float Ws[IN * OUT];
  __shared__ float Hs[ROWS][IN];
  const int tid = threadIdx.x;
  const int NT = ROWS * OUT;
  for (int i = tid; i < IN * OUT; i += NT) Ws[i] = W[i];
  const int row0 = blockIdx.x * ROWS;
  for (int i = tid; i < ROWS * IN; i += NT) {
    int rr = i / IN, kk = i - rr * IN;
    int gr = row0 + rr;
    Hs[rr][kk] = (gr < n) ? h[gr * IN + kk] : 0.0f;
  }
  __syncthreads();
  const int r = tid / OUT, c = tid - r * OUT;
  const int row = row0 + r;
  if (row < n) {
    float acc = 0.0f;
#pragma unroll
    for (int k = 0; k < IN; ++k) acc += Hs[r][k] * Ws[k * OUT + c];
    t[row * OUT + c] = acc * dinv[row];
  }
}

// ---------- gather aggregation, 64 feats ----------
template <bool RELU>
__global__ void k_gather64c(const float* __restrict__ t, const int* __restrict__ rowstart,
                            const int* __restrict__ csr_src,
                            const float* __restrict__ dinv, const float* __restrict__ b,
                            float* __restrict__ out) {
  const int wave = (blockIdx.x * blockDim.x + threadIdx.x) >> 6;
  const int lane = threadIdx.x & 63;
  if (wave >= NN) return;
  const int r0 = rowstart[wave], r1 = rowstart[wave + 1];
  float acc = t[wave * 64 + lane];
  int e = r0;
  for (; e + 3 < r1; e += 4) {
    int s0 = csr_src[e], s1 = csr_src[e + 1], s2 = csr_src[e + 2], s3 = csr_src[e + 3];
    acc += t[s0 * 64 + lane] + t[s1 * 64 + lane] + t[s2 * 64 + lane] + t[s3 * 64 + lane];
  }
  for (; e < r1; ++e) acc += t[csr_src[e] * 64 + lane];
  float v = acc * dinv[wave] + b[lane];
  out[wave * 64 + lane] = RELU ? fmaxf(v, 0.0f) : v;
}

// ---------- layer-3 gather (32 feats) fused with mean-pool partial sums ----------
__global__ void k_gather32_pool(const float* __restrict__ t, const int* __restrict__ rowstart,
                                const int* __restrict__ csr_src,
                                const float* __restrict__ dinv, const float* __restrict__ b,
                                const int* __restrict__ batch, float* __restrict__ psum) {
  const int wave = (blockIdx.x * blockDim.x + threadIdx.x) >> 6;
  const int lane = threadIdx.x & 63;
  if (wave >= NN) return;
  const int f = lane & 31, j = lane >> 5;
  const int r0 = rowstart[wave], r1 = rowstart[wave + 1];
  float acc = (j == 0) ? t[wave * 32 + f] : 0.0f;
  int e = r0 + j;
  for (; e + 3 < r1; e += 4) {
    int s0 = csr_src[e], s1 = csr_src[e + 2];
    acc += t[s0 * 32 + f] + t[s1 * 32 + f];
  }
  for (; e < r1; e += 2) acc += t[csr_src[e] * 32 + f];
  acc += __shfl_xor(acc, 32, 64);
  if (j == 0) {
    float v = acc * dinv[wave] + b[f];
    atomicAdd(&psum[batch[wave] * 32 + f], v);
  }
}

// ---------- counts from sorted batch + final divide ----------
__global__ void k_finalize(const float* __restrict__ psum, const int* __restrict__ batch,
                           float* __restrict__ out) {
  int i = blockIdx.x * blockDim.x + threadIdx.x;
  if (i >= NG * 32) return;
  int g = i >> 5;
  int lo = 0, hi = NN;
  while (lo < hi) { int m = (lo + hi) >> 1; if (batch[m] < g) lo = m + 1; else hi = m; }
  int a = lo;
  lo = 0; hi = NN;
  while (lo < hi) { int m = (lo + hi) >> 1; if (batch[m] < g + 1) lo = m + 1; else hi = m; }
  int cnt = lo - a;
  out[i] = psum[i] / fmaxf((float)cnt, 1.0f);
}

extern "C" void kernel_launch(void* const* d_in, const int* in_sizes, int n_in,
                              void* d_out, int out_size, void* d_ws, size_t ws_size,
                              hipStream_t stream) {
  const float* x  = (const float*)d_in[0];
  const int*   ei = (const int*)d_in[1];
  const int* batch = (const int*)d_in[2];
  const float* W1 = (const float*)d_in[3];
  const float* b1 = (const float*)d_in[4];
  const float* W2 = (const float*)d_in[5];
  const float* b2 = (const float*)d_in[6];
  const float* W3 = (const float*)d_in[7];
  const float* b3 = (const float*)d_in[8];
  float* out = (float*)d_out;

  const int* src = ei;        // edge_index[0]
  const int* dst = ei + NE;   // edge_index[1]

  // workspace layout (element offsets, 4B each)
  float* ws = (float*)d_ws;
  float* dinv     = ws;                          // NN
  int*   degi     = (int*)(ws + 100352);         // NN   (zeroed jointly with gcursor)
  int*   gcursor  = (int*)(ws + 200704);         // NCB
  int*   bsum     = (int*)(ws + 201216);         // NSB (98), written before read
  int*   rowstart = (int*)(ws + 204160);         // NN+1 (16B-aligned)
  int*   csr_src  = (int*)(ws + 304512);         // NE
  float* bufT     = ws + 3504512;                // NN*64 (pairs aliased pre-layer1)
  float* bufH     = ws + 9904512;                // NN*64
  float* psum     = ws + 16304512;               // NG*32
  int*   pairs    = (int*)bufT;

  const int B = 256;
  auto cdiv = [](int a, int b) { return (a + b - 1) / b; };

  // ---- build norm + CSR (shared across all 3 layers) ----
  k_zero_i<<<cdiv(103808, B), B, 0, stream>>>(degi, 103808);  // degi..gcursor incl. pads
  k_degi<<<2048, B, 0, stream>>>(dst, degi, NE);
  k_scan1<<<NSB, 256, 0, stream>>>(degi, rowstart, bsum, dinv);
  k_scan2<<<1, 128, 0, stream>>>(bsum);
  k_scan3<<<NSB, 256, 0, stream>>>(rowstart, bsum);
  k_msplit<<<cdiv(NE, TILE), B, 0, stream>>>(src, dst, rowstart, gcursor, pairs, NE);
  k_bfill<<<NCB, B, 0, stream>>>(pairs, rowstart, csr_src);

  // ---- layer 1: x(13) -> 64, relu ----
  k_mm<13, 64, 4><<<cdiv(NN, 4), B, 0, stream>>>(x, W1, dinv, bufT, NN);
  k_gather64c<true><<<cdiv(NN * 64, B), B, 0, stream>>>(bufT, rowstart, csr_src, dinv, b1, bufH);

  // ---- layer 2: 64 -> 64, relu ----
  k_mm<64, 64, 4><<<cdiv(NN, 4), B, 0, stream>>>(bufH, W2, dinv, bufT, NN);
  k_gather64c<true><<<cdiv(NN * 64, B), B, 0, stream>>>(bufT, rowstart, csr_src, dinv, b2, bufH);

  // ---- layer 3: 64 -> 32, fused with pool partial sums ----
  k_mm<64, 32, 8><<<cdiv(NN, 8), B, 0, stream>>>(bufH, W3, dinv, bufT, NN);
  k_zero_f<<<cdiv(NG * 32, B), B, 0, stream>>>(psum, NG * 32);
  k_gather32_pool<<<cdiv(NN * 64, B), B, 0, stream>>>(bufT, rowstart, csr_src, dinv, b3, batch, psum);

  // ---- finalize mean ----
  k_finalize<<<cdiv(NG * 32, B), B, 0, stream>>>(psum, batch, out);
}

// Round 8
// 603.962 us; speedup vs baseline: 1.7604x; 1.1255x over previous
//
#include <hip/hip_runtime.h>

constexpr int NN = 100000;   // nodes
constexpr int NE = 3200000;  // edges
constexpr int NG = 256;      // graphs
constexpr int NCB = 196;     // coarse buckets: dst>>9 (512 nodes each; 99999>>9 = 195)
constexpr int TILE = 4096;   // edges per msplit block
constexpr int EPT = TILE / 256;

// ---------- zero helper ----------
__global__ void k_zero_i(int* __restrict__ p, int n) {
  int i = blockIdx.x * blockDim.x + threadIdx.x;
  if (i < n) p[i] = 0;
}
__global__ void k_zero_f(float* __restrict__ p, int n) {
  int i = blockIdx.x * blockDim.x + threadIdx.x;
  if (i < n) p[i] = 0.0f;
}

// ---------- coarse histogram (196 buckets) via LDS ----------
__global__ void k_chist(const int* __restrict__ dst, int* __restrict__ chist, int E) {
  __shared__ int h[NCB];
  for (int i = threadIdx.x; i < NCB; i += blockDim.x) h[i] = 0;
  __syncthreads();
  int i = blockIdx.x * blockDim.x + threadIdx.x;
  int stride = gridDim.x * blockDim.x;
  for (; i < E; i += stride) atomicAdd(&h[dst[i] >> 9], 1);
  __syncthreads();
  for (int i = threadIdx.x; i < NCB; i += blockDim.x)
    if (h[i] > 0) atomicAdd(&chist[i], h[i]);
}

// ---------- scan 196 coarse counts -> cbase[197] ----------
__global__ void k_cscan(const int* __restrict__ chist, int* __restrict__ cbase) {
  __shared__ int s[256];
  const int t = threadIdx.x;
  s[t] = (t < NCB) ? chist[t] : 0;
  __syncthreads();
  for (int o = 1; o < 256; o <<= 1) {
    int v = s[t];
    int u = (t >= o) ? s[t - o] : 0;
    __syncthreads();
    s[t] = v + u;
    __syncthreads();
  }
  if (t < NCB) cbase[t] = (t == 0) ? 0 : s[t - 1];
  if (t == 0) cbase[NCB] = NE;
}

// ---------- CSR pass 1: tile-chunked multisplit into coarse-bucket regions ----------
// Packed word: src(17b) | (dst&511)<<17.
__global__ void k_msplit(const int* __restrict__ src, const int* __restrict__ dst,
                         const int* __restrict__ cbase, int* __restrict__ gcursor,
                         int* __restrict__ pairs, int E) {
  constexpr int NT = 256;
  __shared__ int hist[NCB], lbase[NCB], lcur[NCB], gwrite[NCB];
  const int tid = threadIdx.x;
  const int e0 = blockIdx.x * TILE;
  for (int i = tid; i < NCB; i += NT) { hist[i] = 0; lcur[i] = 0; }
  __syncthreads();
  int ls[EPT], ld[EPT];
#pragma unroll
  for (int i = 0; i < EPT; ++i) {
    int e = e0 + i * NT + tid;
    if (e < E) {
      ls[i] = src[e];
      ld[i] = dst[e];
      atomicAdd(&hist[ld[i] >> 9], 1);
    } else {
      ld[i] = -1;
    }
  }
  __syncthreads();
  if (tid == 0) {
    int run = 0;
    for (int c = 0; c < NCB; ++c) { lbase[c] = run; run += hist[c]; }
  }
  __syncthreads();
  for (int c = tid; c < NCB; c += NT) {
    int cnt = hist[c];
    if (cnt > 0) {
      int g = atomicAdd(&gcursor[c], cnt);
      gwrite[c] = cbase[c] + g - lbase[c];
    }
  }
  __syncthreads();
#pragma unroll
  for (int i = 0; i < EPT; ++i) {
    if (ld[i] >= 0) {
      int c = ld[i] >> 9;
      int pos = lbase[c] + atomicAdd(&lcur[c], 1);
      pairs[gwrite[c] + pos] = ls[i] | ((ld[i] & 511) << 17);
    }
  }
}

// ---------- CSR pass 2 (merged): per-bucket degree count + scan + rowstart/dinv + fill ----------
__global__ void k_brow(const int* __restrict__ pairs, const int* __restrict__ cbase,
                       int* __restrict__ rowstart, float* __restrict__ dinv,
                       int* __restrict__ csr_src) {
  __shared__ int deg[512], pre[512], cur[512];
  __shared__ int s[256];
  const int cb = blockIdx.x;
  const int n0 = cb << 9;
  const int tid = threadIdx.x;
  const int e0 = cbase[cb], e1 = cbase[cb + 1];
  for (int i = tid; i < 512; i += 256) { deg[i] = 0; cur[i] = 0; }
  __syncthreads();
  for (int e = e0 + tid; e < e1; e += 256) atomicAdd(&deg[pairs[e] >> 17], 1);
  __syncthreads();
  // scan 512 via 256-thread Hillis-Steele over pair-sums
  int d0 = deg[2 * tid], d1 = deg[2 * tid + 1];
  s[tid] = d0 + d1;
  __syncthreads();
  for (int o = 1; o < 256; o <<= 1) {
    int v = s[tid];
    int u = (tid >= o) ? s[tid - o] : 0;
    __syncthreads();
    s[tid] = v + u;
    __syncthreads();
  }
  int p2 = (tid == 0) ? 0 : s[tid - 1];
  pre[2 * tid] = p2;
  pre[2 * tid + 1] = p2 + d0;
  __syncthreads();
  // write rowstart + dinv (coalesced)
  for (int i = tid; i < 512; i += 256) {
    int n = n0 + i;
    if (n < NN) {
      rowstart[n] = e0 + pre[i];
      dinv[n] = rsqrtf((float)(deg[i] + 1));
    }
  }
  if (cb == NCB - 1 && tid == 0) rowstart[NN] = NE;
  // place csr entries (single-writer region, L2-hot pairs re-read)
  for (int e = e0 + tid; e < e1; e += 256) {
    int w = pairs[e];
    int dl = w >> 17;
    int p = e0 + pre[dl] + atomicAdd(&cur[dl], 1);
    csr_src[p] = w & 0x1FFFF;
  }
}

// ---------- dense transform t' = (h @ W) * dinv[row] ----------
template <int IN, int OUT, int ROWS>
__global__ void k_mm(const float* __restrict__ h, const float* __restrict__ W,
                     const float* __restrict__ dinv, float* __restrict__ t, int n) {
  __shared__ float Ws[IN * OUT];
  __shared__ float Hs[ROWS][IN];
  const int tid = threadIdx.x;
  const int NT = ROWS * OUT;
  for (int i = tid; i < IN * OUT; i += NT) Ws[i] = W[i];
  const int row0 = blockIdx.x * ROWS;
  for (int i = tid; i < ROWS * IN; i += NT) {
    int rr = i / IN, kk = i - rr * IN;
    int gr = row0 + rr;
    Hs[rr][kk] = (gr < n) ? h[gr * IN + kk] : 0.0f;
  }
  __syncthreads();
  const int r = tid / OUT, c = tid - r * OUT;
  const int row = row0 + r;
  if (row < n) {
    float acc = 0.0f;
#pragma unroll
    for (int k = 0; k < IN; ++k) acc += Hs[r][k] * Ws[k * OUT + c];
    t[row * OUT + c] = acc * dinv[row];
  }
}

// ---------- gather aggregation, 64 feats ----------
template <bool RELU>
__global__ void k_gather64c(const float* __restrict__ t, const int* __restrict__ rowstart,
                            const int* __restrict__ csr_src,
                            const float* __restrict__ dinv, const float* __restrict__ b,
                            float* __restrict__ out) {
  const int wave = (blockIdx.x * blockDim.x + threadIdx.x) >> 6;
  const int lane = threadIdx.x & 63;
  if (wave >= NN) return;
  const int r0 = rowstart[wave], r1 = rowstart[wave + 1];
  float acc = t[wave * 64 + lane];
  int e = r0;
  for (; e + 3 < r1; e += 4) {
    int s0 = csr_src[e], s1 = csr_src[e + 1], s2 = csr_src[e + 2], s3 = csr_src[e + 3];
    acc += t[s0 * 64 + lane] + t[s1 * 64 + lane] + t[s2 * 64 + lane] + t[s3 * 64 + lane];
  }
  for (; e < r1; ++e) acc += t[csr_src[e] * 64 + lane];
  float v = acc * dinv[wave] + b[lane];
  out[wave * 64 + lane] = RELU ? fmaxf(v, 0.0f) : v;
}

// ---------- layer-3 gather (32 feats) fused with mean-pool partial sums ----------
__global__ void k_gather32_pool(const float* __restrict__ t, const int* __restrict__ rowstart,
                                const int* __restrict__ csr_src,
                                const float* __restrict__ dinv, const float* __restrict__ b,
                                const int* __restrict__ batch, float* __restrict__ psum) {
  const int wave = (blockIdx.x * blockDim.x + threadIdx.x) >> 6;
  const int lane = threadIdx.x & 63;
  if (wave >= NN) return;
  const int f = lane & 31, j = lane >> 5;
  const int r0 = rowstart[wave], r1 = rowstart[wave + 1];
  float acc = (j == 0) ? t[wave * 32 + f] : 0.0f;
  int e = r0 + j;
  for (; e + 3 < r1; e += 4) {
    int s0 = csr_src[e], s1 = csr_src[e + 2];
    acc += t[s0 * 32 + f] + t[s1 * 32 + f];
  }
  for (; e < r1; e += 2) acc += t[csr_src[e] * 32 + f];
  acc += __shfl_xor(acc, 32, 64);
  if (j == 0) {
    float v = acc * dinv[wave] + b[f];
    atomicAdd(&psum[batch[wave] * 32 + f], v);
  }
}

// ---------- counts from sorted batch + final divide ----------
__global__ void k_finalize(const float* __restrict__ psum, const int* __restrict__ batch,
                           float* __restrict__ out) {
  int i = blockIdx.x * blockDim.x + threadIdx.x;
  if (i >= NG * 32) return;
  int g = i >> 5;
  int lo = 0, hi = NN;
  while (lo < hi) { int m = (lo + hi) >> 1; if (batch[m] < g) lo = m + 1; else hi = m; }
  int a = lo;
  lo = 0; hi = NN;
  while (lo < hi) { int m = (lo + hi) >> 1; if (batch[m] < g + 1) lo = m + 1; else hi = m; }
  int cnt = lo - a;
  out[i] = psum[i] / fmaxf((float)cnt, 1.0f);
}

extern "C" void kernel_launch(void* const* d_in, const int* in_sizes, int n_in,
                              void* d_out, int out_size, void* d_ws, size_t ws_size,
                              hipStream_t stream) {
  const float* x  = (const float*)d_in[0];
  const int*   ei = (const int*)d_in[1];
  const int* batch = (const int*)d_in[2];
  const float* W1 = (const float*)d_in[3];
  const float* b1 = (const float*)d_in[4];
  const float* W2 = (const float*)d_in[5];
  const float* b2 = (const float*)d_in[6];
  const float* W3 = (const float*)d_in[7];
  const float* b3 = (const float*)d_in[8];
  float* out = (float*)d_out;

  const int* src = ei;        // edge_index[0]
  const int* dst = ei + NE;   // edge_index[1]

  // workspace layout (element offsets, 4B each)
  float* ws = (float*)d_ws;
  float* dinv     = ws;                          // NN
  int*   chist    = (int*)(ws + 100352);         // NCB    } zeroed as one 392-int range
  int*   gcursor  = (int*)(ws + 100548);         // NCB    }
  int*   cbase    = (int*)(ws + 100744);         // NCB+1
  int*   rowstart = (int*)(ws + 100944);         // NN+1 (byte off 403776, 16B-aligned)
  int*   csr_src  = (int*)(ws + 201056);         // NE
  float* bufT     = ws + 3401056;                // NN*64 (pairs aliased pre-layer1)
  float* bufH     = ws + 9801056;                // NN*64
  float* psum     = ws + 16201056;               // NG*32
  int*   pairs    = (int*)bufT;

  const int B = 256;
  auto cdiv = [](int a, int b) { return (a + b - 1) / b; };

  // ---- build CSR + norm (shared across all 3 layers) ----
  k_zero_i<<<2, B, 0, stream>>>(chist, 392);          // chist + gcursor
  k_chist<<<512, B, 0, stream>>>(dst, chist, NE);
  k_cscan<<<1, 256, 0, stream>>>(chist, cbase);
  k_msplit<<<cdiv(NE, TILE), B, 0, stream>>>(src, dst, cbase, gcursor, pairs, NE);
  k_brow<<<NCB, B, 0, stream>>>(pairs, cbase, rowstart, dinv, csr_src);

  // ---- layer 1: x(13) -> 64, relu ----
  k_mm<13, 64, 4><<<cdiv(NN, 4), B, 0, stream>>>(x, W1, dinv, bufT, NN);
  k_gather64c<true><<<cdiv(NN * 64, B), B, 0, stream>>>(bufT, rowstart, csr_src, dinv, b1, bufH);

  // ---- layer 2: 64 -> 64, relu ----
  k_mm<64, 64, 4><<<cdiv(NN, 4), B, 0, stream>>>(bufH, W2, dinv, bufT, NN);
  k_gather64c<true><<<cdiv(NN * 64, B), B, 0, stream>>>(bufT, rowstart, csr_src, dinv, b2, bufH);

  // ---- layer 3: 64 -> 32, fused with pool partial sums ----
  k_mm<64, 32, 8><<<cdiv(NN, 8), B, 0, stream>>>(bufH, W3, dinv, bufT, NN);
  k_zero_f<<<cdiv(NG * 32, B), B, 0, stream>>>(psum, NG * 32);
  k_gather32_pool<<<cdiv(NN * 64, B), B, 0, stream>>>(bufT, rowstart, csr_src, dinv, b3, batch, psum);

  // ---- finalize mean ----
  k_finalize<<<cdiv(NG * 32, B), B, 0, stream>>>(psum, batch, out);
}

// Round 9
// 513.796 us; speedup vs baseline: 2.0693x; 1.1755x over previous
//
#include <hip/hip_runtime.h>

constexpr int NN = 100000;   // nodes
constexpr int NE = 3200000;  // edges
constexpr int NG = 256;      // graphs
constexpr int NCB = 196;     // coarse buckets: dst>>9 (512 nodes each; 99999>>9 = 195)
constexpr int TILE = 4096;   // edges per msplit block
constexpr int EPT = TILE / 256;

// ---------- zero helper ----------
__global__ void k_zero_i(int* __restrict__ p, int n) {
  int i = blockIdx.x * blockDim.x + threadIdx.x;
  if (i < n) p[i] = 0;
}

// ---------- coarse histogram (196 buckets) via LDS ----------
__global__ void k_chist(const int* __restrict__ dst, int* __restrict__ chist, int E) {
  __shared__ int h[NCB];
  for (int i = threadIdx.x; i < NCB; i += blockDim.x) h[i] = 0;
  __syncthreads();
  int i = blockIdx.x * blockDim.x + threadIdx.x;
  int stride = gridDim.x * blockDim.x;
  for (; i < E; i += stride) atomicAdd(&h[dst[i] >> 9], 1);
  __syncthreads();
  for (int i = threadIdx.x; i < NCB; i += blockDim.x)
    if (h[i] > 0) atomicAdd(&chist[i], h[i]);
}

// ---------- scan 196 coarse counts -> cbase[197] ----------
__global__ void k_cscan(const int* __restrict__ chist, int* __restrict__ cbase) {
  __shared__ int s[256];
  const int t = threadIdx.x;
  s[t] = (t < NCB) ? chist[t] : 0;
  __syncthreads();
  for (int o = 1; o < 256; o <<= 1) {
    int v = s[t];
    int u = (t >= o) ? s[t - o] : 0;
    __syncthreads();
    s[t] = v + u;
    __syncthreads();
  }
  if (t < NCB) cbase[t] = (t == 0) ? 0 : s[t - 1];
  if (t == 0) cbase[NCB] = NE;
}

// ---------- CSR pass 1: tile-chunked multisplit (src | (dst&511)<<17) ----------
__global__ void k_msplit(const int* __restrict__ src, const int* __restrict__ dst,
                         const int* __restrict__ cbase, int* __restrict__ gcursor,
                         int* __restrict__ pairs, int E) {
  constexpr int NT = 256;
  __shared__ int hist[NCB], lbase[NCB], lcur[NCB], gwrite[NCB];
  const int tid = threadIdx.x;
  const int e0 = blockIdx.x * TILE;
  for (int i = tid; i < NCB; i += NT) { hist[i] = 0; lcur[i] = 0; }
  __syncthreads();
  int ls[EPT], ld[EPT];
#pragma unroll
  for (int i = 0; i < EPT; ++i) {
    int e = e0 + i * NT + tid;
    if (e < E) {
      ls[i] = src[e];
      ld[i] = dst[e];
      atomicAdd(&hist[ld[i] >> 9], 1);
    } else {
      ld[i] = -1;
    }
  }
  __syncthreads();
  if (tid == 0) {
    int run = 0;
    for (int c = 0; c < NCB; ++c) { lbase[c] = run; run += hist[c]; }
  }
  __syncthreads();
  for (int c = tid; c < NCB; c += NT) {
    int cnt = hist[c];
    if (cnt > 0) {
      int g = atomicAdd(&gcursor[c], cnt);
      gwrite[c] = cbase[c] + g - lbase[c];
    }
  }
  __syncthreads();
#pragma unroll
  for (int i = 0; i < EPT; ++i) {
    if (ld[i] >= 0) {
      int c = ld[i] >> 9;
      int pos = lbase[c] + atomicAdd(&lcur[c], 1);
      pairs[gwrite[c] + pos] = ls[i] | ((ld[i] & 511) << 17);
    }
  }
}

// ---------- CSR pass 2: per-bucket degree + scan + rowstart/dinv + fill ----------
__global__ void k_brow(const int* __restrict__ pairs, const int* __restrict__ cbase,
                       int* __restrict__ rowstart, float* __restrict__ dinv,
                       int* __restrict__ csr_src) {
  __shared__ int deg[512], pre[512], cur[512];
  __shared__ int s[256];
  const int cb = blockIdx.x;
  const int n0 = cb << 9;
  const int tid = threadIdx.x;
  const int e0 = cbase[cb], e1 = cbase[cb + 1];
  for (int i = tid; i < 512; i += 256) { deg[i] = 0; cur[i] = 0; }
  __syncthreads();
  for (int e = e0 + tid; e < e1; e += 256) atomicAdd(&deg[pairs[e] >> 17], 1);
  __syncthreads();
  int d0 = deg[2 * tid], d1 = deg[2 * tid + 1];
  s[tid] = d0 + d1;
  __syncthreads();
  for (int o = 1; o < 256; o <<= 1) {
    int v = s[tid];
    int u = (tid >= o) ? s[tid - o] : 0;
    __syncthreads();
    s[tid] = v + u;
    __syncthreads();
  }
  int p2 = (tid == 0) ? 0 : s[tid - 1];
  pre[2 * tid] = p2;
  pre[2 * tid + 1] = p2 + d0;
  __syncthreads();
  for (int i = tid; i < 512; i += 256) {
    int n = n0 + i;
    if (n < NN) {
      rowstart[n] = e0 + pre[i];
      dinv[n] = rsqrtf((float)(deg[i] + 1));
    }
  }
  if (cb == NCB - 1 && tid == 0) rowstart[NN] = NE;
  for (int e = e0 + tid; e < e1; e += 256) {
    int w = pairs[e];
    int dl = w >> 17;
    int p = e0 + pre[dl] + atomicAdd(&cur[dl], 1);
    csr_src[p] = w & 0x1FFFF;
  }
}

// ---------- xs = x * dinv, padded 13 -> 16 ----------
__global__ void k_xs(const float* __restrict__ x, const float* __restrict__ dinv,
                     float* __restrict__ xs) {
  int i = blockIdx.x * blockDim.x + threadIdx.x;
  if (i < NN * 16) {
    int v = i >> 4, f = i & 15;
    xs[i] = (f < 13) ? x[v * 13 + f] * dinv[v] : 0.0f;
  }
}

// ---------- layer-1 aggregation on 16-padded raw features: 4 nodes/wave ----------
// agg[v] = (sum_{s in N(v)} xs[s] + xs[v]) * dinv[v]
__global__ void k_gather16(const float* __restrict__ xs, const int* __restrict__ rowstart,
                           const int* __restrict__ csr_src, const float* __restrict__ dinv,
                           float* __restrict__ agg) {
  const int gid = blockIdx.x * blockDim.x + threadIdx.x;
  const int node = gid >> 4;
  const int f = gid & 15;
  if (node >= NN) return;
  const int r0 = rowstart[node], r1 = rowstart[node + 1];
  float acc = xs[node * 16 + f];
  int e = r0;
  for (; e + 3 < r1; e += 4) {
    int s0 = csr_src[e], s1 = csr_src[e + 1], s2 = csr_src[e + 2], s3 = csr_src[e + 3];
    acc += xs[s0 * 16 + f] + xs[s1 * 16 + f] + xs[s2 * 16 + f] + xs[s3 * 16 + f];
  }
  for (; e < r1; ++e) acc += xs[csr_src[e] * 16 + f];
  agg[node * 16 + f] = acc * dinv[node];
}

// ---------- fused mm1+mm2: t2 = relu(agg@W1 + b1) @ W2 * dinv ----------
__global__ void k_mmfused(const float* __restrict__ agg, const float* __restrict__ W1,
                          const float* __restrict__ b1, const float* __restrict__ W2,
                          const float* __restrict__ dinv, float* __restrict__ t2, int n) {
  __shared__ float Ws1[13 * 64];
  __shared__ float Bs1[64];
  __shared__ float Ws2[64 * 64];
  __shared__ float Hs[4][16];
  __shared__ float H1[4][64];
  const int tid = threadIdx.x;
  for (int i = tid; i < 13 * 64; i += 256) Ws1[i] = W1[i];
  if (tid < 64) Bs1[tid] = b1[tid];
  for (int i = tid; i < 64 * 64; i += 256) Ws2[i] = W2[i];
  const int row0 = blockIdx.x * 4;
  for (int i = tid; i < 4 * 16; i += 256) {
    int rr = i >> 4, kk = i & 15;
    int gr = row0 + rr;
    Hs[rr][kk] = (gr < n) ? agg[gr * 16 + kk] : 0.0f;
  }
  __syncthreads();
  const int r = tid >> 6, c = tid & 63;
  float acc = Bs1[c];
#pragma unroll
  for (int k = 0; k < 13; ++k) acc += Hs[r][k] * Ws1[k * 64 + c];
  H1[r][c] = fmaxf(acc, 0.0f);
  __syncthreads();
  const int row = row0 + r;
  if (row < n) {
    float a2 = 0.0f;
#pragma unroll
    for (int k = 0; k < 64; ++k) a2 += H1[r][k] * Ws2[k * 64 + c];
    t2[row * 64 + c] = a2 * dinv[row];
  }
}

// ---------- dense transform t' = (h @ W) * dinv[row] ----------
template <int IN, int OUT, int ROWS>
__global__ void k_mm(const float* __restrict__ h, const float* __restrict__ W,
                     const float* __restrict__ dinv, float* __restrict__ t, int n) {
  __shared__ float Ws[IN * OUT];
  __shared__ float Hs[ROWS][IN];
  const int tid = threadIdx.x;
  const int NT = ROWS * OUT;
  for (int i = tid; i < IN * OUT; i += NT) Ws[i] = W[i];
  const int row0 = blockIdx.x * ROWS;
  for (int i = tid; i < ROWS * IN; i += NT) {
    int rr = i / IN, kk = i - rr * IN;
    int gr = row0 + rr;
    Hs[rr][kk] = (gr < n) ? h[gr * IN + kk] : 0.0f;
  }
  __syncthreads();
  const int r = tid / OUT, c = tid - r * OUT;
  const int row = row0 + r;
  if (row < n) {
    float acc = 0.0f;
#pragma unroll
    for (int k = 0; k < IN; ++k) acc += Hs[r][k] * Ws[k * OUT + c];
    t[row * OUT + c] = acc * dinv[row];
  }
}

// ---------- gather aggregation, 64 feats ----------
template <bool RELU>
__global__ void k_gather64c(const float* __restrict__ t, const int* __restrict__ rowstart,
                            const int* __restrict__ csr_src,
                            const float* __restrict__ dinv, const float* __restrict__ b,
                            float* __restrict__ out) {
  const int wave = (blockIdx.x * blockDim.x + threadIdx.x) >> 6;
  const int lane = threadIdx.x & 63;
  if (wave >= NN) return;
  const int r0 = rowstart[wave], r1 = rowstart[wave + 1];
  float acc = t[wave * 64 + lane];
  int e = r0;
  for (; e + 3 < r1; e += 4) {
    int s0 = csr_src[e], s1 = csr_src[e + 1], s2 = csr_src[e + 2], s3 = csr_src[e + 3];
    acc += t[s0 * 64 + lane] + t[s1 * 64 + lane] + t[s2 * 64 + lane] + t[s3 * 64 + lane];
  }
  for (; e < r1; ++e) acc += t[csr_src[e] * 64 + lane];
  float v = acc * dinv[wave] + b[lane];
  out[wave * 64 + lane] = RELU ? fmaxf(v, 0.0f) : v;
}

// ---------- layer-3 gather (32 feats), write h3 (no atomics) ----------
__global__ void k_gather32w(const float* __restrict__ t, const int* __restrict__ rowstart,
                            const int* __restrict__ csr_src,
                            const float* __restrict__ dinv, const float* __restrict__ b,
                            float* __restrict__ h3) {
  const int wave = (blockIdx.x * blockDim.x + threadIdx.x) >> 6;
  const int lane = threadIdx.x & 63;
  if (wave >= NN) return;
  const int f = lane & 31, j = lane >> 5;
  const int r0 = rowstart[wave], r1 = rowstart[wave + 1];
  float acc = (j == 0) ? t[wave * 32 + f] : 0.0f;
  int e = r0 + j;
  for (; e + 3 < r1; e += 4) {
    int s0 = csr_src[e], s1 = csr_src[e + 2];
    acc += t[s0 * 32 + f] + t[s1 * 32 + f];
  }
  for (; e < r1; e += 2) acc += t[csr_src[e] * 32 + f];
  acc += __shfl_xor(acc, 32, 64);
  if (j == 0) h3[wave * 32 + f] = acc * dinv[wave] + b[f];
}

// ---------- per-graph mean pool (batch sorted -> contiguous ranges) ----------
__global__ void k_pool(const float* __restrict__ h3, const int* __restrict__ batch,
                       float* __restrict__ out) {
  const int g = blockIdx.x;
  int lo = 0, hi = NN;
  while (lo < hi) { int m = (lo + hi) >> 1; if (batch[m] < g) lo = m + 1; else hi = m; }
  const int a = lo;
  lo = 0; hi = NN;
  while (lo < hi) { int m = (lo + hi) >> 1; if (batch[m] < g + 1) lo = m + 1; else hi = m; }
  const int bEnd = lo;
  const int tid = threadIdx.x;
  const int nl = tid >> 5, f = tid & 31;
  float acc = 0.0f;
  for (int n = a + nl; n < bEnd; n += 8) acc += h3[n * 32 + f];
  __shared__ float red[8][32];
  red[nl][f] = acc;
  __syncthreads();
  if (tid < 32) {
    float s = 0.0f;
#pragma unroll
    for (int i = 0; i < 8; ++i) s += red[i][f];
    int cnt = bEnd - a;
    out[g * 32 + f] = s / fmaxf((float)cnt, 1.0f);
  }
}

extern "C" void kernel_launch(void* const* d_in, const int* in_sizes, int n_in,
                              void* d_out, int out_size, void* d_ws, size_t ws_size,
                              hipStream_t stream) {
  const float* x  = (const float*)d_in[0];
  const int*   ei = (const int*)d_in[1];
  const int* batch = (const int*)d_in[2];
  const float* W1 = (const float*)d_in[3];
  const float* b1 = (const float*)d_in[4];
  const float* W2 = (const float*)d_in[5];
  const float* b2 = (const float*)d_in[6];
  const float* W3 = (const float*)d_in[7];
  const float* b3 = (const float*)d_in[8];
  float* out = (float*)d_out;

  const int* src = ei;        // edge_index[0]
  const int* dst = ei + NE;   // edge_index[1]

  // workspace layout (element offsets, 4B each) -- max extent 16201056 floats (64.8 MB)
  float* ws = (float*)d_ws;
  float* dinv     = ws;                          // NN
  int*   chist    = (int*)(ws + 100352);         // NCB } zeroed as one range
  int*   gcursor  = (int*)(ws + 100548);         // NCB }
  int*   cbase    = (int*)(ws + 100744);         // NCB+1
  int*   rowstart = (int*)(ws + 100944);         // NN+1
  int*   csr_src  = (int*)(ws + 201056);         // NE               ends 3401056
  float* bufT     = ws + 3401056;                // NN*64            ends 9801056
  float* bufH     = ws + 9801056;                // NN*64            ends 16201056
  // aliases (lifetimes disjoint):
  int*   pairs = (int*)bufT;                     // [3401056, 6601056) dead after k_brow
  float* t3    = bufT;                           // [3401056, 6601056) after t2 dead
  float* h3    = bufT + 3200000;                 // [6601056, 9801056)
  float* xs    = bufH;                           // [9801056, 11401056) dead after gather16
  float* agg1  = bufH + 1600000;                 // [11401056,13001056) dead after mmfused
  float* t2    = bufT;                           // full bufT
  float* h2    = bufH;                           // full bufH (overwrites xs/agg1, dead)

  const int B = 256;
  auto cdiv = [](int a, int b) { return (a + b - 1) / b; };

  // ---- build CSR + norm (shared across all 3 layers) ----
  k_zero_i<<<2, B, 0, stream>>>(chist, 392);
  k_chist<<<512, B, 0, stream>>>(dst, chist, NE);
  k_cscan<<<1, 256, 0, stream>>>(chist, cbase);
  k_msplit<<<cdiv(NE, TILE), B, 0, stream>>>(src, dst, cbase, gcursor, pairs, NE);
  k_brow<<<NCB, B, 0, stream>>>(pairs, cbase, rowstart, dinv, csr_src);

  // ---- layer 1 (aggregate-first): xs -> agg1 -> fused mm1+mm2 -> t2 ----
  k_xs<<<cdiv(NN * 16, B), B, 0, stream>>>(x, dinv, xs);
  k_gather16<<<cdiv(NN * 16, B), B, 0, stream>>>(xs, rowstart, csr_src, dinv, agg1);
  k_mmfused<<<cdiv(NN, 4), B, 0, stream>>>(agg1, W1, b1, W2, dinv, t2, NN);

  // ---- layer 2 aggregation: t2 -> h2 (relu, +b2) ----
  k_gather64c<true><<<cdiv(NN * 64, B), B, 0, stream>>>(t2, rowstart, csr_src, dinv, b2, h2);

  // ---- layer 3: mm 64->32 then gather (write), then pool ----
  k_mm<64, 32, 8><<<cdiv(NN, 8), B, 0, stream>>>(h2, W3, dinv, t3, NN);
  k_gather32w<<<cdiv(NN * 64, B), B, 0, stream>>>(t3, rowstart, csr_src, dinv, b3, h3);
  k_pool<<<NG, B, 0, stream>>>(h3, batch, out);
}

// Round 10
// 447.939 us; speedup vs baseline: 2.3736x; 1.1470x over previous
//
#include <hip/hip_runtime.h>
#include <hip/hip_fp16.h>

constexpr int NN = 100000;   // nodes
constexpr int NE = 3200000;  // edges
constexpr int NG = 256;      // graphs
constexpr int NCB = 196;     // coarse buckets: dst>>9 (512 nodes each; 99999>>9 = 195)
constexpr int TILE = 4096;   // edges per msplit block
constexpr int EPT = TILE / 256;

// ---------- zero helper ----------
__global__ void k_zero_i(int* __restrict__ p, int n) {
  int i = blockIdx.x * blockDim.x + threadIdx.x;
  if (i < n) p[i] = 0;
}

// ---------- coarse histogram (196 buckets) via LDS ----------
__global__ void k_chist(const int* __restrict__ dst, int* __restrict__ chist, int E) {
  __shared__ int h[NCB];
  for (int i = threadIdx.x; i < NCB; i += blockDim.x) h[i] = 0;
  __syncthreads();
  int i = blockIdx.x * blockDim.x + threadIdx.x;
  int stride = gridDim.x * blockDim.x;
  for (; i < E; i += stride) atomicAdd(&h[dst[i] >> 9], 1);
  __syncthreads();
  for (int i = threadIdx.x; i < NCB; i += blockDim.x)
    if (h[i] > 0) atomicAdd(&chist[i], h[i]);
}

// ---------- scan 196 coarse counts -> cbase[197] ----------
__global__ void k_cscan(const int* __restrict__ chist, int* __restrict__ cbase) {
  __shared__ int s[256];
  const int t = threadIdx.x;
  s[t] = (t < NCB) ? chist[t] : 0;
  __syncthreads();
  for (int o = 1; o < 256; o <<= 1) {
    int v = s[t];
    int u = (t >= o) ? s[t - o] : 0;
    __syncthreads();
    s[t] = v + u;
    __syncthreads();
  }
  if (t < NCB) cbase[t] = (t == 0) ? 0 : s[t - 1];
  if (t == 0) cbase[NCB] = NE;
}

// ---------- CSR pass 1: tile-chunked multisplit (src | (dst&511)<<17) ----------
__global__ void k_msplit(const int* __restrict__ src, const int* __restrict__ dst,
                         const int* __restrict__ cbase, int* __restrict__ gcursor,
                         int* __restrict__ pairs, int E) {
  constexpr int NT = 256;
  __shared__ int hist[NCB], lbase[NCB], lcur[NCB], gwrite[NCB];
  const int tid = threadIdx.x;
  const int e0 = blockIdx.x * TILE;
  for (int i = tid; i < NCB; i += NT) { hist[i] = 0; lcur[i] = 0; }
  __syncthreads();
  int ls[EPT], ld[EPT];
#pragma unroll
  for (int i = 0; i < EPT; ++i) {
    int e = e0 + i * NT + tid;
    if (e < E) {
      ls[i] = src[e];
      ld[i] = dst[e];
      atomicAdd(&hist[ld[i] >> 9], 1);
    } else {
      ld[i] = -1;
    }
  }
  __syncthreads();
  if (tid == 0) {
    int run = 0;
    for (int c = 0; c < NCB; ++c) { lbase[c] = run; run += hist[c]; }
  }
  __syncthreads();
  for (int c = tid; c < NCB; c += NT) {
    int cnt = hist[c];
    if (cnt > 0) {
      int g = atomicAdd(&gcursor[c], cnt);
      gwrite[c] = cbase[c] + g - lbase[c];
    }
  }
  __syncthreads();
#pragma unroll
  for (int i = 0; i < EPT; ++i) {
    if (ld[i] >= 0) {
      int c = ld[i] >> 9;
      int pos = lbase[c] + atomicAdd(&lcur[c], 1);
      pairs[gwrite[c] + pos] = ls[i] | ((ld[i] & 511) << 17);
    }
  }
}

// ---------- CSR pass 2: per-bucket degree + scan + rowstart/dinv + fill ----------
__global__ void k_brow(const int* __restrict__ pairs, const int* __restrict__ cbase,
                       int* __restrict__ rowstart, float* __restrict__ dinv,
                       int* __restrict__ csr_src) {
  __shared__ int deg[512], pre[512], cur[512];
  __shared__ int s[256];
  const int cb = blockIdx.x;
  const int n0 = cb << 9;
  const int tid = threadIdx.x;
  const int e0 = cbase[cb], e1 = cbase[cb + 1];
  for (int i = tid; i < 512; i += 256) { deg[i] = 0; cur[i] = 0; }
  __syncthreads();
  for (int e = e0 + tid; e < e1; e += 256) atomicAdd(&deg[pairs[e] >> 17], 1);
  __syncthreads();
  int d0 = deg[2 * tid], d1 = deg[2 * tid + 1];
  s[tid] = d0 + d1;
  __syncthreads();
  for (int o = 1; o < 256; o <<= 1) {
    int v = s[tid];
    int u = (tid >= o) ? s[tid - o] : 0;
    __syncthreads();
    s[tid] = v + u;
    __syncthreads();
  }
  int p2 = (tid == 0) ? 0 : s[tid - 1];
  pre[2 * tid] = p2;
  pre[2 * tid + 1] = p2 + d0;
  __syncthreads();
  for (int i = tid; i < 512; i += 256) {
    int n = n0 + i;
    if (n < NN) {
      rowstart[n] = e0 + pre[i];
      dinv[n] = rsqrtf((float)(deg[i] + 1));
    }
  }
  if (cb == NCB - 1 && tid == 0) rowstart[NN] = NE;
  for (int e = e0 + tid; e < e1; e += 256) {
    int w = pairs[e];
    int dl = w >> 17;
    int p = e0 + pre[dl] + atomicAdd(&cur[dl], 1);
    csr_src[p] = w & 0x1FFFF;
  }
}

// ---------- xs = x * dinv (fp16), padded 13 -> 16 ----------
__global__ void k_xs(const float* __restrict__ x, const float* __restrict__ dinv,
                     __half* __restrict__ xs) {
  int i = blockIdx.x * blockDim.x + threadIdx.x;
  if (i < NN * 16) {
    int v = i >> 4, f = i & 15;
    float val = (f < 13) ? x[v * 13 + f] * dinv[v] : 0.0f;
    xs[i] = __float2half_rn(val);
  }
}

// ---------- layer-1 aggregation on 16-padded fp16 features: 4 nodes/wave ----------
__global__ void k_gather16(const __half* __restrict__ xs, const int* __restrict__ rowstart,
                           const int* __restrict__ csr_src, const float* __restrict__ dinv,
                           float* __restrict__ agg) {
  const int gid = blockIdx.x * blockDim.x + threadIdx.x;
  const int node = gid >> 4;
  const int f = gid & 15;
  if (node >= NN) return;
  const int r0 = rowstart[node], r1 = rowstart[node + 1];
  float acc = __half2float(xs[node * 16 + f]);
  int e = r0;
  for (; e + 7 < r1; e += 8) {
    int s0 = csr_src[e], s1 = csr_src[e + 1], s2 = csr_src[e + 2], s3 = csr_src[e + 3];
    int s4 = csr_src[e + 4], s5 = csr_src[e + 5], s6 = csr_src[e + 6], s7 = csr_src[e + 7];
    float v0 = __half2float(xs[s0 * 16 + f]), v1 = __half2float(xs[s1 * 16 + f]);
    float v2 = __half2float(xs[s2 * 16 + f]), v3 = __half2float(xs[s3 * 16 + f]);
    float v4 = __half2float(xs[s4 * 16 + f]), v5 = __half2float(xs[s5 * 16 + f]);
    float v6 = __half2float(xs[s6 * 16 + f]), v7 = __half2float(xs[s7 * 16 + f]);
    acc += ((v0 + v1) + (v2 + v3)) + ((v4 + v5) + (v6 + v7));
  }
  for (; e < r1; ++e) acc += __half2float(xs[csr_src[e] * 16 + f]);
  agg[node * 16 + f] = acc * dinv[node];
}

// ---------- fused mm1+mm2: t2 = fp16( relu(agg@W1 + b1) @ W2 * dinv ) ----------
__global__ void k_mmfused(const float* __restrict__ agg, const float* __restrict__ W1,
                          const float* __restrict__ b1, const float* __restrict__ W2,
                          const float* __restrict__ dinv, __half* __restrict__ t2, int n) {
  __shared__ float Ws1[13 * 64];
  __shared__ float Bs1[64];
  __shared__ float Ws2[64 * 64];
  __shared__ float Hs[4][16];
  __shared__ float H1[4][64];
  const int tid = threadIdx.x;
  for (int i = tid; i < 13 * 64; i += 256) Ws1[i] = W1[i];
  if (tid < 64) Bs1[tid] = b1[tid];
  for (int i = tid; i < 64 * 64; i += 256) Ws2[i] = W2[i];
  const int row0 = blockIdx.x * 4;
  for (int i = tid; i < 4 * 16; i += 256) {
    int rr = i >> 4, kk = i & 15;
    int gr = row0 + rr;
    Hs[rr][kk] = (gr < n) ? agg[gr * 16 + kk] : 0.0f;
  }
  __syncthreads();
  const int r = tid >> 6, c = tid & 63;
  float acc = Bs1[c];
#pragma unroll
  for (int k = 0; k < 13; ++k) acc += Hs[r][k] * Ws1[k * 64 + c];
  H1[r][c] = fmaxf(acc, 0.0f);
  __syncthreads();
  const int row = row0 + r;
  if (row < n) {
    float a2 = 0.0f;
#pragma unroll
    for (int k = 0; k < 64; ++k) a2 += H1[r][k] * Ws2[k * 64 + c];
    t2[row * 64 + c] = __float2half_rn(a2 * dinv[row]);
  }
}

// ---------- gather aggregation, 64 feats, fp16 in / fp16 out ----------
__global__ void k_gather64h(const __half* __restrict__ t, const int* __restrict__ rowstart,
                            const int* __restrict__ csr_src,
                            const float* __restrict__ dinv, const float* __restrict__ b,
                            __half* __restrict__ out) {
  const int wave = (blockIdx.x * blockDim.x + threadIdx.x) >> 6;
  const int lane = threadIdx.x & 63;
  if (wave >= NN) return;
  const int r0 = rowstart[wave], r1 = rowstart[wave + 1];
  float acc = __half2float(t[wave * 64 + lane]);
  int e = r0;
  for (; e + 7 < r1; e += 8) {
    int s0 = csr_src[e], s1 = csr_src[e + 1], s2 = csr_src[e + 2], s3 = csr_src[e + 3];
    int s4 = csr_src[e + 4], s5 = csr_src[e + 5], s6 = csr_src[e + 6], s7 = csr_src[e + 7];
    float v0 = __half2float(t[s0 * 64 + lane]), v1 = __half2float(t[s1 * 64 + lane]);
    float v2 = __half2float(t[s2 * 64 + lane]), v3 = __half2float(t[s3 * 64 + lane]);
    float v4 = __half2float(t[s4 * 64 + lane]), v5 = __half2float(t[s5 * 64 + lane]);
    float v6 = __half2float(t[s6 * 64 + lane]), v7 = __half2float(t[s7 * 64 + lane]);
    acc += ((v0 + v1) + (v2 + v3)) + ((v4 + v5) + (v6 + v7));
  }
  for (; e < r1; ++e) acc += __half2float(t[csr_src[e] * 64 + lane]);
  float v = acc * dinv[wave] + b[lane];
  out[wave * 64 + lane] = __float2half_rn(fmaxf(v, 0.0f));  // relu (layer 2 only)
}

// ---------- dense transform fp16->fp16: t = (h @ W) * dinv ----------
template <int IN, int OUT, int ROWS>
__global__ void k_mm_hh(const __half* __restrict__ h, const float* __restrict__ W,
                        const float* __restrict__ dinv, __half* __restrict__ t, int n) {
  __shared__ float Ws[IN * OUT];
  __shared__ float Hs[ROWS][IN];
  const int tid = threadIdx.x;
  const int NT = ROWS * OUT;
  for (int i = tid; i < IN * OUT; i += NT) Ws[i] = W[i];
  const int row0 = blockIdx.x * ROWS;
  for (int i = tid; i < ROWS * IN; i += NT) {
    int rr = i / IN, kk = i - rr * IN;
    int gr = row0 + rr;
    Hs[rr][kk] = (gr < n) ? __half2float(h[gr * IN + kk]) : 0.0f;
  }
  __syncthreads();
  const int r = tid / OUT, c = tid - r * OUT;
  const int row = row0 + r;
  if (row < n) {
    float acc = 0.0f;
#pragma unroll
    for (int k = 0; k < IN; ++k) acc += Hs[r][k] * Ws[k * OUT + c];
    t[row * OUT + c] = __float2half_rn(acc * dinv[row]);
  }
}

// ---------- layer-3 gather (32 feats fp16), write h3 f32 ----------
__global__ void k_gather32w(const __half* __restrict__ t, const int* __restrict__ rowstart,
                            const int* __restrict__ csr_src,
                            const float* __restrict__ dinv, const float* __restrict__ b,
                            float* __restrict__ h3) {
  const int wave = (blockIdx.x * blockDim.x + threadIdx.x) >> 6;
  const int lane = threadIdx.x & 63;
  if (wave >= NN) return;
  const int f = lane & 31, j = lane >> 5;
  const int r0 = rowstart[wave], r1 = rowstart[wave + 1];
  float acc = (j == 0) ? __half2float(t[wave * 32 + f]) : 0.0f;
  int e = r0 + j;
  for (; e + 6 < r1; e += 8) {
    int s0 = csr_src[e], s1 = csr_src[e + 2], s2 = csr_src[e + 4], s3 = csr_src[e + 6];
    float v0 = __half2float(t[s0 * 32 + f]), v1 = __half2float(t[s1 * 32 + f]);
    float v2 = __half2float(t[s2 * 32 + f]), v3 = __half2float(t[s3 * 32 + f]);
    acc += (v0 + v1) + (v2 + v3);
  }
  for (; e < r1; e += 2) acc += __half2float(t[csr_src[e] * 32 + f]);
  acc += __shfl_xor(acc, 32, 64);
  if (j == 0) h3[wave * 32 + f] = acc * dinv[wave] + b[f];
}

// ---------- per-graph mean pool (batch sorted -> contiguous ranges) ----------
__global__ void k_pool(const float* __restrict__ h3, const int* __restrict__ batch,
                       float* __restrict__ out) {
  const int g = blockIdx.x;
  int lo = 0, hi = NN;
  while (lo < hi) { int m = (lo + hi) >> 1; if (batch[m] < g) lo = m + 1; else hi = m; }
  const int a = lo;
  lo = 0; hi = NN;
  while (lo < hi) { int m = (lo + hi) >> 1; if (batch[m] < g + 1) lo = m + 1; else hi = m; }
  const int bEnd = lo;
  const int tid = threadIdx.x;
  const int nl = tid >> 5, f = tid & 31;
  float acc = 0.0f;
  for (int n = a + nl; n < bEnd; n += 8) acc += h3[n * 32 + f];
  __shared__ float red[8][32];
  red[nl][f] = acc;
  __syncthreads();
  if (tid < 32) {
    float s = 0.0f;
#pragma unroll
    for (int i = 0; i < 8; ++i) s += red[i][f];
    int cnt = bEnd - a;
    out[g * 32 + f] = s / fmaxf((float)cnt, 1.0f);
  }
}

extern "C" void kernel_launch(void* const* d_in, const int* in_sizes, int n_in,
                              void* d_out, int out_size, void* d_ws, size_t ws_size,
                              hipStream_t stream) {
  const float* x  = (const float*)d_in[0];
  const int*   ei = (const int*)d_in[1];
  const int* batch = (const int*)d_in[2];
  const float* W1 = (const float*)d_in[3];
  const float* b1 = (const float*)d_in[4];
  const float* W2 = (const float*)d_in[5];
  const float* b2 = (const float*)d_in[6];
  const float* W3 = (const float*)d_in[7];
  const float* b3 = (const float*)d_in[8];
  float* out = (float*)d_out;

  const int* src = ei;        // edge_index[0]
  const int* dst = ei + NE;   // edge_index[1]

  // workspace layout (element offsets, 4B floats) -- extent same as R9 (64.8 MB)
  float* ws = (float*)d_ws;
  float* dinv     = ws;                          // NN
  int*   chist    = (int*)(ws + 100352);         // NCB } zeroed as one range
  int*   gcursor  = (int*)(ws + 100548);         // NCB }
  int*   cbase    = (int*)(ws + 100744);         // NCB+1
  int*   rowstart = (int*)(ws + 100944);         // NN+1
  int*   csr_src  = (int*)(ws + 201056);         // NE            ends 3401056
  float* bufT     = ws + 3401056;                // NN*64 floats  ends 9801056
  float* bufH     = ws + 9801056;                // NN*64 floats  ends 16201056
  // aliases (lifetimes disjoint):
  int*    pairs = (int*)bufT;                    // [3401056,6601056) dead after brow
  __half* t2    = (__half*)bufT;                 // NN*64 halves = [3401056,5001056)
  __half* t3    = (__half*)bufT;                 // NN*32 halves = [3401056,4201056) (t2 dead)
  float*  h3    = bufT + 1600000;                // NN*32 floats = [5001056,8201056)
  __half* xs    = (__half*)bufH;                 // NN*16 halves = [9801056,10601056)
  float*  agg1  = bufH + 1600000;                // NN*16 floats = [11401056,13001056)
  __half* h2    = (__half*)bufH;                 // NN*64 halves (xs/agg1 dead)

  const int B = 256;
  auto cdiv = [](int a, int b) { return (a + b - 1) / b; };

  // ---- build CSR + norm (shared across all 3 layers) ----
  k_zero_i<<<2, B, 0, stream>>>(chist, 392);
  k_chist<<<512, B, 0, stream>>>(dst, chist, NE);
  k_cscan<<<1, 256, 0, stream>>>(chist, cbase);
  k_msplit<<<cdiv(NE, TILE), B, 0, stream>>>(src, dst, cbase, gcursor, pairs, NE);
  k_brow<<<NCB, B, 0, stream>>>(pairs, cbase, rowstart, dinv, csr_src);

  // ---- layer 1 (aggregate-first): xs(fp16) -> agg1 -> fused mm1+mm2 -> t2(fp16) ----
  k_xs<<<cdiv(NN * 16, B), B, 0, stream>>>(x, dinv, xs);
  k_gather16<<<cdiv(NN * 16, B), B, 0, stream>>>(xs, rowstart, csr_src, dinv, agg1);
  k_mmfused<<<cdiv(NN, 4), B, 0, stream>>>(agg1, W1, b1, W2, dinv, t2, NN);

  // ---- layer 2 aggregation: t2 -> h2 (relu, +b2), fp16 ----
  k_gather64h<<<cdiv(NN * 64, B), B, 0, stream>>>(t2, rowstart, csr_src, dinv, b2, h2);

  // ---- layer 3: mm 64->32 (fp16->fp16) then gather (write f32), then pool ----
  k_mm_hh<64, 32, 8><<<cdiv(NN, 8), B, 0, stream>>>(h2, W3, dinv, t3, NN);
  k_gather32w<<<cdiv(NN * 64, B), B, 0, stream>>>(t3, rowstart, csr_src, dinv, b3, h3);
  k_pool<<<NG, B, 0, stream>>>(h3, batch, out);
}

// Round 11
// 425.592 us; speedup vs baseline: 2.4982x; 1.0525x over previous
//
#include <hip/hip_runtime.h>
#include <hip/hip_fp16.h>

constexpr int NN = 100000;   // nodes
constexpr int NE = 3200000;  // edges
constexpr int NG = 256;      // graphs
constexpr int NCB = 196;     // coarse buckets: dst>>9 (512 nodes each; 99999>>9 = 195)
constexpr int TILE = 4096;   // edges per msplit block
constexpr int EPT = TILE / 256;

// ---------- zero helper ----------
__global__ void k_zero_i(int* __restrict__ p, int n) {
  int i = blockIdx.x * blockDim.x + threadIdx.x;
  if (i < n) p[i] = 0;
}

// ---------- coarse histogram (196 buckets) via LDS ----------
__global__ void k_chist(const int* __restrict__ dst, int* __restrict__ chist, int E) {
  __shared__ int h[NCB];
  for (int i = threadIdx.x; i < NCB; i += blockDim.x) h[i] = 0;
  __syncthreads();
  int i = blockIdx.x * blockDim.x + threadIdx.x;
  int stride = gridDim.x * blockDim.x;
  for (; i < E; i += stride) atomicAdd(&h[dst[i] >> 9], 1);
  __syncthreads();
  for (int i = threadIdx.x; i < NCB; i += blockDim.x)
    if (h[i] > 0) atomicAdd(&chist[i], h[i]);
}

// ---------- scan 196 coarse counts -> cbase[197] ----------
__global__ void k_cscan(const int* __restrict__ chist, int* __restrict__ cbase) {
  __shared__ int s[256];
  const int t = threadIdx.x;
  s[t] = (t < NCB) ? chist[t] : 0;
  __syncthreads();
  for (int o = 1; o < 256; o <<= 1) {
    int v = s[t];
    int u = (t >= o) ? s[t - o] : 0;
    __syncthreads();
    s[t] = v + u;
    __syncthreads();
  }
  if (t < NCB) cbase[t] = (t == 0) ? 0 : s[t - 1];
  if (t == 0) cbase[NCB] = NE;
}

// ---------- CSR pass 1: multisplit with LDS staging (coalesced writes) ----------
__global__ void k_msplit(const int* __restrict__ src, const int* __restrict__ dst,
                         const int* __restrict__ cbase, int* __restrict__ gcursor,
                         int* __restrict__ pairs, int E) {
  constexpr int NT = 256;
  __shared__ int hist[NCB], lbase[NCB], lcur[NCB], gwrite[NCB];
  __shared__ int staged[TILE];
  __shared__ unsigned char sbid[TILE];
  __shared__ int stot;
  const int tid = threadIdx.x;
  const int e0 = blockIdx.x * TILE;
  for (int i = tid; i < NCB; i += NT) { hist[i] = 0; lcur[i] = 0; }
  __syncthreads();
  int ls[EPT], ld[EPT];
#pragma unroll
  for (int i = 0; i < EPT; ++i) {
    int e = e0 + i * NT + tid;
    if (e < E) {
      ls[i] = src[e];
      ld[i] = dst[e];
      atomicAdd(&hist[ld[i] >> 9], 1);
    } else {
      ld[i] = -1;
    }
  }
  __syncthreads();
  if (tid == 0) {
    int run = 0;
    for (int c = 0; c < NCB; ++c) { lbase[c] = run; run += hist[c]; }
    stot = run;
  }
  __syncthreads();
  for (int c = tid; c < NCB; c += NT) {
    int cnt = hist[c];
    if (cnt > 0) {
      int g = atomicAdd(&gcursor[c], cnt);
      gwrite[c] = cbase[c] + g;  // this block's chunk start in bucket c
    }
  }
  __syncthreads();
#pragma unroll
  for (int i = 0; i < EPT; ++i) {
    if (ld[i] >= 0) {
      int c = ld[i] >> 9;
      int pos = lbase[c] + atomicAdd(&lcur[c], 1);
      staged[pos] = ls[i] | ((ld[i] & 511) << 17);
      sbid[pos] = (unsigned char)c;
    }
  }
  __syncthreads();
  // linear write-out: consecutive staged slots -> consecutive global addresses
  const int total = stot;
  for (int i = tid; i < total; i += NT) {
    int c = sbid[i];
    pairs[gwrite[c] + (i - lbase[c])] = staged[i];
  }
}

// ---------- CSR pass 2: per-bucket degree + scan + rowstart/dinv + fill ----------
__global__ void k_brow(const int* __restrict__ pairs, const int* __restrict__ cbase,
                       int* __restrict__ rowstart, float* __restrict__ dinv,
                       int* __restrict__ csr_src) {
  __shared__ int deg[512], pre[512], cur[512];
  __shared__ int s[256];
  const int cb = blockIdx.x;
  const int n0 = cb << 9;
  const int tid = threadIdx.x;
  const int e0 = cbase[cb], e1 = cbase[cb + 1];
  for (int i = tid; i < 512; i += 256) { deg[i] = 0; cur[i] = 0; }
  __syncthreads();
  for (int e = e0 + tid; e < e1; e += 256) atomicAdd(&deg[pairs[e] >> 17], 1);
  __syncthreads();
  int d0 = deg[2 * tid], d1 = deg[2 * tid + 1];
  s[tid] = d0 + d1;
  __syncthreads();
  for (int o = 1; o < 256; o <<= 1) {
    int v = s[tid];
    int u = (tid >= o) ? s[tid - o] : 0;
    __syncthreads();
    s[tid] = v + u;
    __syncthreads();
  }
  int p2 = (tid == 0) ? 0 : s[tid - 1];
  pre[2 * tid] = p2;
  pre[2 * tid + 1] = p2 + d0;
  __syncthreads();
  for (int i = tid; i < 512; i += 256) {
    int n = n0 + i;
    if (n < NN) {
      rowstart[n] = e0 + pre[i];
      dinv[n] = rsqrtf((float)(deg[i] + 1));
    }
  }
  if (cb == NCB - 1 && tid == 0) rowstart[NN] = NE;
  for (int e = e0 + tid; e < e1; e += 256) {
    int w = pairs[e];
    int dl = w >> 17;
    int p = e0 + pre[dl] + atomicAdd(&cur[dl], 1);
    csr_src[p] = w & 0x1FFFF;
  }
}

// ---------- xs = x * dinv (fp16), padded 13 -> 16 ----------
__global__ void k_xs(const float* __restrict__ x, const float* __restrict__ dinv,
                     __half* __restrict__ xs) {
  int i = blockIdx.x * blockDim.x + threadIdx.x;
  if (i < NN * 16) {
    int v = i >> 4, f = i & 15;
    float val = (f < 13) ? x[v * 13 + f] * dinv[v] : 0.0f;
    xs[i] = __float2half_rn(val);
  }
}

// ---------- layer-1 aggregation: 1 node/wave, 8 edges in flight, half2 lanes ----------
__global__ void k_gather16(const __half* __restrict__ xs, const int* __restrict__ rowstart,
                           const int* __restrict__ csr_src, const float* __restrict__ dinv,
                           float* __restrict__ agg) {
  const int node = (blockIdx.x * blockDim.x + threadIdx.x) >> 6;
  const int lane = threadIdx.x & 63;
  if (node >= NN) return;
  const int fp = lane & 7;    // feature pair (8 half2 = 16 feats)
  const int es = lane >> 3;   // edge slot 0..7
  const __half2* x2 = (const __half2*)xs;
  const int r0 = rowstart[node], r1 = rowstart[node + 1];
  float ax = 0.0f, ay = 0.0f;
  if (es == 0) {
    float2 sf = __half22float2(x2[node * 8 + fp]);
    ax = sf.x; ay = sf.y;
  }
  int e = r0 + es;
  for (; e + 8 < r1; e += 16) {
    int s0 = csr_src[e], s1 = csr_src[e + 8];
    float2 v0 = __half22float2(x2[s0 * 8 + fp]);
    float2 v1 = __half22float2(x2[s1 * 8 + fp]);
    ax += v0.x + v1.x; ay += v0.y + v1.y;
  }
  for (; e < r1; e += 8) {
    float2 v = __half22float2(x2[csr_src[e] * 8 + fp]);
    ax += v.x; ay += v.y;
  }
  ax += __shfl_xor(ax, 32); ay += __shfl_xor(ay, 32);
  ax += __shfl_xor(ax, 16); ay += __shfl_xor(ay, 16);
  ax += __shfl_xor(ax, 8);  ay += __shfl_xor(ay, 8);
  if (lane < 8) {
    const float di = dinv[node];
    ((float2*)agg)[node * 8 + lane] = make_float2(ax * di, ay * di);
  }
}

// ---------- fused mm1+mm2: t2 = fp16( relu(agg@W1 + b1) @ W2 * dinv ) ----------
__global__ void k_mmfused(const float* __restrict__ agg, const float* __restrict__ W1,
                          const float* __restrict__ b1, const float* __restrict__ W2,
                          const float* __restrict__ dinv, __half* __restrict__ t2, int n) {
  __shared__ float Ws1[13 * 64];
  __shared__ float Bs1[64];
  __shared__ float Ws2[64 * 64];
  __shared__ float Hs[4][16];
  __shared__ float H1[4][64];
  const int tid = threadIdx.x;
  for (int i = tid; i < 13 * 64; i += 256) Ws1[i] = W1[i];
  if (tid < 64) Bs1[tid] = b1[tid];
  for (int i = tid; i < 64 * 64; i += 256) Ws2[i] = W2[i];
  const int row0 = blockIdx.x * 4;
  for (int i = tid; i < 4 * 16; i += 256) {
    int rr = i >> 4, kk = i & 15;
    int gr = row0 + rr;
    Hs[rr][kk] = (gr < n) ? agg[gr * 16 + kk] : 0.0f;
  }
  __syncthreads();
  const int r = tid >> 6, c = tid & 63;
  float acc = Bs1[c];
#pragma unroll
  for (int k = 0; k < 13; ++k) acc += Hs[r][k] * Ws1[k * 64 + c];
  H1[r][c] = fmaxf(acc, 0.0f);
  __syncthreads();
  const int row = row0 + r;
  if (row < n) {
    float a2 = 0.0f;
#pragma unroll
    for (int k = 0; k < 64; ++k) a2 += H1[r][k] * Ws2[k * 64 + c];
    t2[row * 64 + c] = __float2half_rn(a2 * dinv[row]);
  }
}

// ---------- layer-2 gather: 1 node/wave, 2 edges in flight, half2 lanes, relu ----------
__global__ void k_gather64h(const __half* __restrict__ t, const int* __restrict__ rowstart,
                            const int* __restrict__ csr_src,
                            const float* __restrict__ dinv, const float* __restrict__ b,
                            __half* __restrict__ out) {
  const int node = (blockIdx.x * blockDim.x + threadIdx.x) >> 6;
  const int lane = threadIdx.x & 63;
  if (node >= NN) return;
  const int fp = lane & 31;   // feature pair (32 half2 = 64 feats)
  const int es = lane >> 5;   // edge slot 0..1
  const __half2* t2 = (const __half2*)t;
  const int r0 = rowstart[node], r1 = rowstart[node + 1];
  float ax = 0.0f, ay = 0.0f;
  if (es == 0) {
    float2 sf = __half22float2(t2[node * 32 + fp]);
    ax = sf.x; ay = sf.y;
  }
  int e = r0 + es;
  for (; e + 6 < r1; e += 8) {  // 4 per lane = 8 edges per wave-iter
    int s0 = csr_src[e], s1 = csr_src[e + 2], s2 = csr_src[e + 4], s3 = csr_src[e + 6];
    float2 v0 = __half22float2(t2[s0 * 32 + fp]);
    float2 v1 = __half22float2(t2[s1 * 32 + fp]);
    float2 v2 = __half22float2(t2[s2 * 32 + fp]);
    float2 v3 = __half22float2(t2[s3 * 32 + fp]);
    ax += (v0.x + v1.x) + (v2.x + v3.x);
    ay += (v0.y + v1.y) + (v2.y + v3.y);
  }
  for (; e < r1; e += 2) {
    float2 v = __half22float2(t2[csr_src[e] * 32 + fp]);
    ax += v.x; ay += v.y;
  }
  ax += __shfl_xor(ax, 32); ay += __shfl_xor(ay, 32);
  if (es == 0) {
    const float di = dinv[node];
    float2 bb = ((const float2*)b)[fp];
    float vx = fmaxf(ax * di + bb.x, 0.0f);
    float vy = fmaxf(ay * di + bb.y, 0.0f);
    ((__half2*)out)[node * 32 + fp] = __floats2half2_rn(vx, vy);
  }
}

// ---------- dense transform fp16->fp16: t = (h @ W) * dinv ----------
template <int IN, int OUT, int ROWS>
__global__ void k_mm_hh(const __half* __restrict__ h, const float* __restrict__ W,
                        const float* __restrict__ dinv, __half* __restrict__ t, int n) {
  __shared__ float Ws[IN * OUT];
  __shared__ float Hs[ROWS][IN];
  const int tid = threadIdx.x;
  const int NT = ROWS * OUT;
  for (int i = tid; i < IN * OUT; i += NT) Ws[i] = W[i];
  const int row0 = blockIdx.x * ROWS;
  for (int i = tid; i < ROWS * IN; i += NT) {
    int rr = i / IN, kk = i - rr * IN;
    int gr = row0 + rr;
    Hs[rr][kk] = (gr < n) ? __half2float(h[gr * IN + kk]) : 0.0f;
  }
  __syncthreads();
  const int r = tid / OUT, c = tid - r * OUT;
  const int row = row0 + r;
  if (row < n) {
    float acc = 0.0f;
#pragma unroll
    for (int k = 0; k < IN; ++k) acc += Hs[r][k] * Ws[k * OUT + c];
    t[row * OUT + c] = __float2half_rn(acc * dinv[row]);
  }
}

// ---------- layer-3 gather: 1 node/wave, 4 edges in flight, half2; write h3 f32 ----------
__global__ void k_gather32w(const __half* __restrict__ t, const int* __restrict__ rowstart,
                            const int* __restrict__ csr_src,
                            const float* __restrict__ dinv, const float* __restrict__ b,
                            float* __restrict__ h3) {
  const int node = (blockIdx.x * blockDim.x + threadIdx.x) >> 6;
  const int lane = threadIdx.x & 63;
  if (node >= NN) return;
  const int fp = lane & 15;   // feature pair (16 half2 = 32 feats)
  const int es = lane >> 4;   // edge slot 0..3
  const __half2* t2 = (const __half2*)t;
  const int r0 = rowstart[node], r1 = rowstart[node + 1];
  float ax = 0.0f, ay = 0.0f;
  if (es == 0) {
    float2 sf = __half22float2(t2[node * 16 + fp]);
    ax = sf.x; ay = sf.y;
  }
  int e = r0 + es;
  for (; e + 4 < r1; e += 8) {  // 2 per lane = 8 edges per wave-iter
    int s0 = csr_src[e], s1 = csr_src[e + 4];
    float2 v0 = __half22float2(t2[s0 * 16 + fp]);
    float2 v1 = __half22float2(t2[s1 * 16 + fp]);
    ax += v0.x + v1.x; ay += v0.y + v1.y;
  }
  for (; e < r1; e += 4) {
    float2 v = __half22float2(t2[csr_src[e] * 16 + fp]);
    ax += v.x; ay += v.y;
  }
  ax += __shfl_xor(ax, 32); ay += __shfl_xor(ay, 32);
  ax += __shfl_xor(ax, 16); ay += __shfl_xor(ay, 16);
  if (lane < 16) {
    const float di = dinv[node];
    float2 bb = ((const float2*)b)[fp];
    ((float2*)h3)[node * 16 + fp] = make_float2(ax * di + bb.x, ay * di + bb.y);
  }
}

// ---------- per-graph mean pool (batch sorted -> contiguous ranges) ----------
__global__ void k_pool(const float* __restrict__ h3, const int* __restrict__ batch,
                       float* __restrict__ out) {
  const int g = blockIdx.x;
  int lo = 0, hi = NN;
  while (lo < hi) { int m = (lo + hi) >> 1; if (batch[m] < g) lo = m + 1; else hi = m; }
  const int a = lo;
  lo = 0; hi = NN;
  while (lo < hi) { int m = (lo + hi) >> 1; if (batch[m] < g + 1) lo = m + 1; else hi = m; }
  const int bEnd = lo;
  const int tid = threadIdx.x;
  const int nl = tid >> 5, f = tid & 31;
  float acc = 0.0f;
  for (int n = a + nl; n < bEnd; n += 8) acc += h3[n * 32 + f];
  __shared__ float red[8][32];
  red[nl][f] = acc;
  __syncthreads();
  if (tid < 32) {
    float s = 0.0f;
#pragma unroll
    for (int i = 0; i < 8; ++i) s += red[i][f];
    int cnt = bEnd - a;
    out[g * 32 + f] = s / fmaxf((float)cnt, 1.0f);
  }
}

extern "C" void kernel_launch(void* const* d_in, const int* in_sizes, int n_in,
                              void* d_out, int out_size, void* d_ws, size_t ws_size,
                              hipStream_t stream) {
  const float* x  = (const float*)d_in[0];
  const int*   ei = (const int*)d_in[1];
  const int* batch = (const int*)d_in[2];
  const float* W1 = (const float*)d_in[3];
  const float* b1 = (const float*)d_in[4];
  const float* W2 = (const float*)d_in[5];
  const float* b2 = (const float*)d_in[6];
  const float* W3 = (const float*)d_in[7];
  const float* b3 = (const float*)d_in[8];
  float* out = (float*)d_out;

  const int* src = ei;        // edge_index[0]
  const int* dst = ei + NE;   // edge_index[1]

  // workspace layout (element offsets, 4B floats) -- extent 64.8 MB
  float* ws = (float*)d_ws;
  float* dinv     = ws;                          // NN
  int*   chist    = (int*)(ws + 100352);         // NCB } zeroed as one range
  int*   gcursor  = (int*)(ws + 100548);         // NCB }
  int*   cbase    = (int*)(ws + 100744);         // NCB+1
  int*   rowstart = (int*)(ws + 100944);         // NN+1
  int*   csr_src  = (int*)(ws + 201056);         // NE            ends 3401056
  float* bufT     = ws + 3401056;                // NN*64 floats  ends 9801056
  float* bufH     = ws + 9801056;                // NN*64 floats  ends 16201056
  // aliases (lifetimes disjoint):
  int*    pairs = (int*)bufT;                    // dead after brow
  __half* t2    = (__half*)bufT;                 // NN*64 halves
  __half* t3    = (__half*)bufT;                 // NN*32 halves (t2 dead)
  float*  h3    = bufT + 1600000;                // NN*32 floats
  __half* xs    = (__half*)bufH;                 // NN*16 halves, dead after gather16
  float*  agg1  = bufH + 1600000;                // NN*16 floats, dead after mmfused
  __half* h2    = (__half*)bufH;                 // NN*64 halves (xs/agg1 dead)

  const int B = 256;
  auto cdiv = [](int a, int b) { return (a + b - 1) / b; };

  // ---- build CSR + norm (shared across all 3 layers) ----
  k_zero_i<<<2, B, 0, stream>>>(chist, 392);
  k_chist<<<512, B, 0, stream>>>(dst, chist, NE);
  k_cscan<<<1, 256, 0, stream>>>(chist, cbase);
  k_msplit<<<cdiv(NE, TILE), B, 0, stream>>>(src, dst, cbase, gcursor, pairs, NE);
  k_brow<<<NCB, B, 0, stream>>>(pairs, cbase, rowstart, dinv, csr_src);

  // ---- layer 1 (aggregate-first): xs(fp16) -> agg1 -> fused mm1+mm2 -> t2(fp16) ----
  k_xs<<<cdiv(NN * 16, B), B, 0, stream>>>(x, dinv, xs);
  k_gather16<<<cdiv(NN * 64, B), B, 0, stream>>>(xs, rowstart, csr_src, dinv, agg1);
  k_mmfused<<<cdiv(NN, 4), B, 0, stream>>>(agg1, W1, b1, W2, dinv, t2, NN);

  // ---- layer 2 aggregation: t2 -> h2 (relu, +b2), fp16 ----
  k_gather64h<<<cdiv(NN * 64, B), B, 0, stream>>>(t2, rowstart, csr_src, dinv, b2, h2);

  // ---- layer 3: mm 64->32 (fp16->fp16) then gather (write f32), then pool ----
  k_mm_hh<64, 32, 8><<<cdiv(NN, 8), B, 0, stream>>>(h2, W3, dinv, t3, NN);
  k_gather32w<<<cdiv(NN * 64, B), B, 0, stream>>>(t3, rowstart, csr_src, dinv, b3, h3);
  k_pool<<<NG, B, 0, stream>>>(h3, batch, out);
}

// Round 12
// 366.018 us; speedup vs baseline: 2.9048x; 1.1628x over previous
//
#include <hip/hip_runtime.h>
#include <hip/hip_fp16.h>

constexpr int NN = 100000;   // nodes
constexpr int NE = 3200000;  // edges
constexpr int NG = 256;      // graphs
constexpr int NCB = 196;     // coarse buckets: dst>>9 (512 nodes each; 99999>>9 = 195)
constexpr int TILE = 4096;   // edges per msplit block
constexpr int EPT = TILE / 256;
constexpr int CAP = 17408;   // per-bucket slot capacity (mean 16327 + 8.5 sigma)

// ---------- zero helper ----------
__global__ void k_zero_i(int* __restrict__ p, int n) {
  int i = blockIdx.x * blockDim.x + threadIdx.x;
  if (i < n) p[i] = 0;
}

// ---------- scan 196 bucket totals (gcursor) -> cbase[197] ----------
__global__ void k_cscan(const int* __restrict__ gcursor, int* __restrict__ cbase) {
  __shared__ int s[256];
  const int t = threadIdx.x;
  s[t] = (t < NCB) ? gcursor[t] : 0;
  __syncthreads();
  for (int o = 1; o < 256; o <<= 1) {
    int v = s[t];
    int u = (t >= o) ? s[t - o] : 0;
    __syncthreads();
    s[t] = v + u;
    __syncthreads();
  }
  if (t < NCB) cbase[t] = (t == 0) ? 0 : s[t - 1];
  if (t == 0) cbase[NCB] = NE;
}

// ---------- CSR pass 1: multisplit into fixed-capacity bucket regions ----------
// LDS-staged bucket-ordered write-out (coalesced). Packed: src | (dst&511)<<17.
__global__ void k_msplit(const int* __restrict__ src, const int* __restrict__ dst,
                         int* __restrict__ gcursor, int* __restrict__ pairs, int E) {
  constexpr int NT = 256;
  __shared__ int hist[NCB], lbase[NCB], lcur[NCB], gwrite[NCB];
  __shared__ int staged[TILE];
  __shared__ unsigned char sbid[TILE];
  __shared__ int stot;
  const int tid = threadIdx.x;
  const int e0 = blockIdx.x * TILE;
  for (int i = tid; i < NCB; i += NT) { hist[i] = 0; lcur[i] = 0; }
  __syncthreads();
  int ls[EPT], ld[EPT];
#pragma unroll
  for (int i = 0; i < EPT; ++i) {
    int e = e0 + i * NT + tid;
    if (e < E) {
      ls[i] = src[e];
      ld[i] = dst[e];
      atomicAdd(&hist[ld[i] >> 9], 1);
    } else {
      ld[i] = -1;
    }
  }
  __syncthreads();
  if (tid == 0) {
    int run = 0;
    for (int c = 0; c < NCB; ++c) { lbase[c] = run; run += hist[c]; }
    stot = run;
  }
  __syncthreads();
  for (int c = tid; c < NCB; c += NT) {
    int cnt = hist[c];
    if (cnt > 0) {
      int g = atomicAdd(&gcursor[c], cnt);
      gwrite[c] = c * CAP + g;  // fixed-capacity region, no cbase dependency
    }
  }
  __syncthreads();
#pragma unroll
  for (int i = 0; i < EPT; ++i) {
    if (ld[i] >= 0) {
      int c = ld[i] >> 9;
      int pos = lbase[c] + atomicAdd(&lcur[c], 1);
      staged[pos] = ls[i] | ((ld[i] & 511) << 17);
      sbid[pos] = (unsigned char)c;
    }
  }
  __syncthreads();
  const int total = stot;
  for (int i = tid; i < total; i += NT) {
    int c = sbid[i];
    pairs[gwrite[c] + (i - lbase[c])] = staged[i];
  }
}

// ---------- CSR pass 2: per-bucket degree + scan + rowstart/dinv + packed fill ----------
__global__ void k_brow(const int* __restrict__ pairs, const int* __restrict__ cbase,
                       int* __restrict__ rowstart, float* __restrict__ dinv,
                       int* __restrict__ csr_src) {
  __shared__ int deg[512], pre[512], cur[512];
  __shared__ int s[256];
  const int cb = blockIdx.x;
  const int n0 = cb << 9;
  const int tid = threadIdx.x;
  const int e0 = cbase[cb];
  const int cnt = cbase[cb + 1] - e0;
  const int p0 = cb * CAP;
  for (int i = tid; i < 512; i += 256) { deg[i] = 0; cur[i] = 0; }
  __syncthreads();
  for (int e = tid; e < cnt; e += 256) atomicAdd(&deg[pairs[p0 + e] >> 17], 1);
  __syncthreads();
  int d0 = deg[2 * tid], d1 = deg[2 * tid + 1];
  s[tid] = d0 + d1;
  __syncthreads();
  for (int o = 1; o < 256; o <<= 1) {
    int v = s[tid];
    int u = (tid >= o) ? s[tid - o] : 0;
    __syncthreads();
    s[tid] = v + u;
    __syncthreads();
  }
  int p2 = (tid == 0) ? 0 : s[tid - 1];
  pre[2 * tid] = p2;
  pre[2 * tid + 1] = p2 + d0;
  __syncthreads();
  for (int i = tid; i < 512; i += 256) {
    int n = n0 + i;
    if (n < NN) {
      rowstart[n] = e0 + pre[i];
      dinv[n] = rsqrtf((float)(deg[i] + 1));
    }
  }
  if (cb == NCB - 1 && tid == 0) rowstart[NN] = NE;
  for (int e = tid; e < cnt; e += 256) {
    int w = pairs[p0 + e];
    int dl = w >> 17;
    int p = e0 + pre[dl] + atomicAdd(&cur[dl], 1);
    csr_src[p] = w & 0x1FFFF;
  }
}

// ---------- xs = x * dinv (fp16), padded 13 -> 16 ----------
__global__ void k_xs(const float* __restrict__ x, const float* __restrict__ dinv,
                     __half* __restrict__ xs) {
  int i = blockIdx.x * blockDim.x + threadIdx.x;
  if (i < NN * 16) {
    int v = i >> 4, f = i & 15;
    float val = (f < 13) ? x[v * 13 + f] * dinv[v] : 0.0f;
    xs[i] = __float2half_rn(val);
  }
}

// ---------- layer-1 aggregation: 1 node/wave, 8 edge slots, 4 loads in flight ----------
__global__ void k_gather16(const __half* __restrict__ xs, const int* __restrict__ rowstart,
                           const int* __restrict__ csr_src, const float* __restrict__ dinv,
                           float* __restrict__ agg) {
  const int node = (blockIdx.x * blockDim.x + threadIdx.x) >> 6;
  const int lane = threadIdx.x & 63;
  if (node >= NN) return;
  const int fp = lane & 7;    // feature pair (8 half2 = 16 feats)
  const int es = lane >> 3;   // edge slot 0..7
  const __half2* x2 = (const __half2*)xs;
  const int r0 = rowstart[node], r1 = rowstart[node + 1];
  float ax = 0.0f, ay = 0.0f;
  if (es == 0) {
    float2 sf = __half22float2(x2[node * 8 + fp]);
    ax = sf.x; ay = sf.y;
  }
  int e = r0 + es;
  for (; e + 24 < r1; e += 32) {  // 4 loads/lane in flight = 32 edges/wave-iter
    int s0 = csr_src[e], s1 = csr_src[e + 8], s2 = csr_src[e + 16], s3 = csr_src[e + 24];
    float2 v0 = __half22float2(x2[s0 * 8 + fp]);
    float2 v1 = __half22float2(x2[s1 * 8 + fp]);
    float2 v2 = __half22float2(x2[s2 * 8 + fp]);
    float2 v3 = __half22float2(x2[s3 * 8 + fp]);
    ax += (v0.x + v1.x) + (v2.x + v3.x);
    ay += (v0.y + v1.y) + (v2.y + v3.y);
  }
  for (; e < r1; e += 8) {
    float2 v = __half22float2(x2[csr_src[e] * 8 + fp]);
    ax += v.x; ay += v.y;
  }
  ax += __shfl_xor(ax, 32); ay += __shfl_xor(ay, 32);
  ax += __shfl_xor(ax, 16); ay += __shfl_xor(ay, 16);
  ax += __shfl_xor(ax, 8);  ay += __shfl_xor(ay, 8);
  if (lane < 8) {
    const float di = dinv[node];
    ((float2*)agg)[node * 8 + lane] = make_float2(ax * di, ay * di);
  }
}

// ---------- fused mm1+mm2: t2 = fp16( relu(agg@W1 + b1) @ W2 * dinv ) ----------
__global__ void k_mmfused(const float* __restrict__ agg, const float* __restrict__ W1,
                          const float* __restrict__ b1, const float* __restrict__ W2,
                          const float* __restrict__ dinv, __half* __restrict__ t2, int n) {
  __shared__ float Ws1[13 * 64];
  __shared__ float Bs1[64];
  __shared__ float Ws2[64 * 64];
  __shared__ float Hs[4][16];
  __shared__ float H1[4][64];
  const int tid = threadIdx.x;
  for (int i = tid; i < 13 * 64; i += 256) Ws1[i] = W1[i];
  if (tid < 64) Bs1[tid] = b1[tid];
  for (int i = tid; i < 64 * 64; i += 256) Ws2[i] = W2[i];
  const int row0 = blockIdx.x * 4;
  for (int i = tid; i < 4 * 16; i += 256) {
    int rr = i >> 4, kk = i & 15;
    int gr = row0 + rr;
    Hs[rr][kk] = (gr < n) ? agg[gr * 16 + kk] : 0.0f;
  }
  __syncthreads();
  const int r = tid >> 6, c = tid & 63;
  float acc = Bs1[c];
#pragma unroll
  for (int k = 0; k < 13; ++k) acc += Hs[r][k] * Ws1[k * 64 + c];
  H1[r][c] = fmaxf(acc, 0.0f);
  __syncthreads();
  const int row = row0 + r;
  if (row < n) {
    float a2 = 0.0f;
#pragma unroll
    for (int k = 0; k < 64; ++k) a2 += H1[r][k] * Ws2[k * 64 + c];
    t2[row * 64 + c] = __float2half_rn(a2 * dinv[row]);
  }
}

// ---------- layer-2 gather FUSED with mm3: t3 = (relu(Â t2 + b2) @ W3) * dinv ----------
// 1 node/wave, 8 row-loads in flight per lane; h2 row staged in LDS for the matvec.
// Grid is EXACT (25000 blocks x 4 nodes = NN), so no early return -> barrier-safe.
__global__ void __launch_bounds__(256) k_gather64m(
    const __half* __restrict__ t, const int* __restrict__ rowstart,
    const int* __restrict__ csr_src, const float* __restrict__ dinv,
    const float* __restrict__ b2, const float* __restrict__ W3,
    __half* __restrict__ t3) {
  __shared__ float W3s[64 * 32];
  __shared__ float h2s[4][64];
  const int tid = threadIdx.x;
  for (int i = tid; i < 64 * 32; i += 256) W3s[i] = W3[i];
  const int w = tid >> 6;
  const int lane = tid & 63;
  const int node = blockIdx.x * 4 + w;
  const int fp = lane & 31;   // feature pair (32 half2 = 64 feats)
  const int es = lane >> 5;   // edge slot 0..1
  const __half2* t2 = (const __half2*)t;
  const int r0 = rowstart[node], r1 = rowstart[node + 1];
  float ax = 0.0f, ay = 0.0f;
  if (es == 0) {
    float2 sf = __half22float2(t2[node * 32 + fp]);
    ax = sf.x; ay = sf.y;
  }
  int e = r0 + es;
  for (; e + 14 < r1; e += 16) {  // 8 loads/lane in flight = 16 edges/wave-iter
    int s0 = csr_src[e],      s1 = csr_src[e + 2],  s2 = csr_src[e + 4],  s3 = csr_src[e + 6];
    int s4 = csr_src[e + 8],  s5 = csr_src[e + 10], s6 = csr_src[e + 12], s7 = csr_src[e + 14];
    float2 v0 = __half22float2(t2[s0 * 32 + fp]);
    float2 v1 = __half22float2(t2[s1 * 32 + fp]);
    float2 v2 = __half22float2(t2[s2 * 32 + fp]);
    float2 v3 = __half22float2(t2[s3 * 32 + fp]);
    float2 v4 = __half22float2(t2[s4 * 32 + fp]);
    float2 v5 = __half22float2(t2[s5 * 32 + fp]);
    float2 v6 = __half22float2(t2[s6 * 32 + fp]);
    float2 v7 = __half22float2(t2[s7 * 32 + fp]);
    ax += ((v0.x + v1.x) + (v2.x + v3.x)) + ((v4.x + v5.x) + (v6.x + v7.x));
    ay += ((v0.y + v1.y) + (v2.y + v3.y)) + ((v4.y + v5.y) + (v6.y + v7.y));
  }
  for (; e < r1; e += 2) {
    float2 v = __half22float2(t2[csr_src[e] * 32 + fp]);
    ax += v.x; ay += v.y;
  }
  ax += __shfl_xor(ax, 32); ay += __shfl_xor(ay, 32);
  const float di = dinv[node];
  if (es == 0) {
    float2 bb = ((const float2*)b2)[fp];
    h2s[w][2 * fp]     = fmaxf(ax * di + bb.x, 0.0f);
    h2s[w][2 * fp + 1] = fmaxf(ay * di + bb.y, 0.0f);
  }
  __syncthreads();  // h2s + W3s visible
  // matvec: lane (j, kh): partial over k = kh*32..kh*32+31, combine halves
  const int j = lane & 31, kh = lane >> 5;
  float p = 0.0f;
#pragma unroll
  for (int k2 = 0; k2 < 32; ++k2) {
    int k = kh * 32 + k2;
    p += h2s[w][k] * W3s[k * 32 + j];  // h2s broadcast, W3s stride-1: conflict-free
  }
  p += __shfl_xor(p, 32);
  if (lane < 32) t3[node * 32 + j] = __float2half_rn(p * di);
}

// ---------- layer-3 gather: 1 node/wave, 4 edge slots, 4 loads in flight; h3 f32 ----------
__global__ void k_gather32w(const __half* __restrict__ t, const int* __restrict__ rowstart,
                            const int* __restrict__ csr_src,
                            const float* __restrict__ dinv, const float* __restrict__ b,
                            float* __restrict__ h3) {
  const int node = (blockIdx.x * blockDim.x + threadIdx.x) >> 6;
  const int lane = threadIdx.x & 63;
  if (node >= NN) return;
  const int fp = lane & 15;   // feature pair (16 half2 = 32 feats)
  const int es = lane >> 4;   // edge slot 0..3
  const __half2* t2 = (const __half2*)t;
  const int r0 = rowstart[node], r1 = rowstart[node + 1];
  float ax = 0.0f, ay = 0.0f;
  if (es == 0) {
    float2 sf = __half22float2(t2[node * 16 + fp]);
    ax = sf.x; ay = sf.y;
  }
  int e = r0 + es;
  for (; e + 12 < r1; e += 16) {  // 4 loads/lane in flight = 16 edges/wave-iter
    int s0 = csr_src[e], s1 = csr_src[e + 4], s2 = csr_src[e + 8], s3 = csr_src[e + 12];
    float2 v0 = __half22float2(t2[s0 * 16 + fp]);
    float2 v1 = __half22float2(t2[s1 * 16 + fp]);
    float2 v2 = __half22float2(t2[s2 * 16 + fp]);
    float2 v3 = __half22float2(t2[s3 * 16 + fp]);
    ax += (v0.x + v1.x) + (v2.x + v3.x);
    ay += (v0.y + v1.y) + (v2.y + v3.y);
  }
  for (; e < r1; e += 4) {
    float2 v = __half22float2(t2[csr_src[e] * 16 + fp]);
    ax += v.x; ay += v.y;
  }
  ax += __shfl_xor(ax, 32); ay += __shfl_xor(ay, 32);
  ax += __shfl_xor(ax, 16); ay += __shfl_xor(ay, 16);
  if (lane < 16) {
    const float di = dinv[node];
    float2 bb = ((const float2*)b)[fp];
    ((float2*)h3)[node * 16 + fp] = make_float2(ax * di + bb.x, ay * di + bb.y);
  }
}

// ---------- per-graph mean pool (batch sorted -> contiguous ranges) ----------
__global__ void k_pool(const float* __restrict__ h3, const int* __restrict__ batch,
                       float* __restrict__ out) {
  const int g = blockIdx.x;
  int lo = 0, hi = NN;
  while (lo < hi) { int m = (lo + hi) >> 1; if (batch[m] < g) lo = m + 1; else hi = m; }
  const int a = lo;
  lo = 0; hi = NN;
  while (lo < hi) { int m = (lo + hi) >> 1; if (batch[m] < g + 1) lo = m + 1; else hi = m; }
  const int bEnd = lo;
  const int tid = threadIdx.x;
  const int nl = tid >> 5, f = tid & 31;
  float acc = 0.0f;
  for (int n = a + nl; n < bEnd; n += 8) acc += h3[n * 32 + f];
  __shared__ float red[8][32];
  red[nl][f] = acc;
  __syncthreads();
  if (tid < 32) {
    float s = 0.0f;
#pragma unroll
    for (int i = 0; i < 8; ++i) s += red[i][f];
    int cnt = bEnd - a;
    out[g * 32 + f] = s / fmaxf((float)cnt, 1.0f);
  }
}

extern "C" void kernel_launch(void* const* d_in, const int* in_sizes, int n_in,
                              void* d_out, int out_size, void* d_ws, size_t ws_size,
                              hipStream_t stream) {
  const float* x  = (const float*)d_in[0];
  const int*   ei = (const int*)d_in[1];
  const int* batch = (const int*)d_in[2];
  const float* W1 = (const float*)d_in[3];
  const float* b1 = (const float*)d_in[4];
  const float* W2 = (const float*)d_in[5];
  const float* b2 = (const float*)d_in[6];
  const float* W3 = (const float*)d_in[7];
  const float* b3 = (const float*)d_in[8];
  float* out = (float*)d_out;

  const int* src = ei;        // edge_index[0]
  const int* dst = ei + NE;   // edge_index[1]

  // workspace layout (element offsets, 4B floats) -- extent 64.8 MB
  float* ws = (float*)d_ws;
  float* dinv     = ws;                          // NN
  int*   gcursor  = (int*)(ws + 100352);         // NCB (zeroed each call)
  int*   cbase    = (int*)(ws + 100608);         // NCB+1
  int*   rowstart = (int*)(ws + 100944);         // NN+1
  int*   csr_src  = (int*)(ws + 201056);         // NE              ends 3401056
  float* bufT     = ws + 3401056;                // NN*64 floats    ends 9801056
  float* bufH     = ws + 9801056;                // NN*64 floats    ends 16201056
  // aliases (lifetimes disjoint):
  int*    pairs = (int*)bufT;                    // NCB*CAP = 3,411,968 ints, dead after brow
  __half* t2    = (__half*)bufT;                 // NN*64 halves  [3401056, 5001056)
  float*  h3    = bufT + 1600000;                // NN*32 floats  [5001056, 8201056)
  __half* xs    = (__half*)bufH;                 // NN*16 halves, dead after gather16
  float*  agg1  = bufH + 1600000;                // NN*16 floats, dead after mmfused
  __half* t3    = (__half*)bufH;                 // NN*32 halves  [9801056,10601056) (xs dead)

  const int B = 256;
  auto cdiv = [](int a, int b) { return (a + b - 1) / b; };

  // ---- build CSR + norm (shared across all 3 layers) ----
  k_zero_i<<<1, B, 0, stream>>>(gcursor, NCB);
  k_msplit<<<cdiv(NE, TILE), B, 0, stream>>>(src, dst, gcursor, pairs, NE);
  k_cscan<<<1, 256, 0, stream>>>(gcursor, cbase);
  k_brow<<<NCB, B, 0, stream>>>(pairs, cbase, rowstart, dinv, csr_src);

  // ---- layer 1 (aggregate-first): xs(fp16) -> agg1 -> fused mm1+mm2 -> t2(fp16) ----
  k_xs<<<cdiv(NN * 16, B), B, 0, stream>>>(x, dinv, xs);
  k_gather16<<<cdiv(NN * 64, B), B, 0, stream>>>(xs, rowstart, csr_src, dinv, agg1);
  k_mmfused<<<cdiv(NN, 4), B, 0, stream>>>(agg1, W1, b1, W2, dinv, t2, NN);

  // ---- layer 2 aggregation fused with mm3: t2 -> t3(fp16) ----
  k_gather64m<<<NN / 4, B, 0, stream>>>(t2, rowstart, csr_src, dinv, b2, W3, t3);

  // ---- layer 3 aggregation: t3 -> h3(f32), then pool ----
  k_gather32w<<<cdiv(NN * 64, B), B, 0, stream>>>(t3, rowstart, csr_src, dinv, b3, h3);
  k_pool<<<NG, B, 0, stream>>>(h3, batch, out);
}